// Round 5
// baseline (726.766 us; speedup 1.0000x reference)
//
#include <hip/hip_runtime.h>
#include <hip/hip_bf16.h>

#define NN 50000      // nodes
#define NE 500000     // edges (without self loops)
#define EP (NE + NN)  // edges with self loops
#define NB 50         // graphs
#define NEG 0.2f
#define NBLK_SCAN 196  // ceil(NN/256)
#define DEFER_THR 8.0f

typedef __attribute__((ext_vector_type(8))) short short8;
typedef __attribute__((ext_vector_type(4))) float f32x4;

__device__ __forceinline__ ushort f2bf(float f) {
  unsigned u = __float_as_uint(f);
  unsigned r = (u + 0x7FFFu + ((u >> 16) & 1u)) >> 16;
  return (ushort)r;
}
__device__ __forceinline__ float bf2f(ushort b) {
  return __uint_as_float(((unsigned)b) << 16);
}

// ---------- mean(edge_attr) : sum into esum[0] ----------
__global__ __launch_bounds__(256) void reduce_sum_kernel(const float* __restrict__ ea,
                                                         float* __restrict__ esum) {
  int t = blockIdx.x * 256 + threadIdx.x;
  float v = 0.f;
  for (int i = t; i < NE; i += gridDim.x * 256) v += ea[i];
  for (int off = 1; off < 64; off <<= 1) v += __shfl_xor(v, off, 64);
  if ((threadIdx.x & 63) == 0) atomicAdd(esum, v);
}

// ---------- weight convert+transpose: W[K][256] f32 -> Wt[256][K] bf16 ----------
__global__ __launch_bounds__(256) void wconv_kernel(const float* __restrict__ W,
                                                    int kshift,  // log2(K)
                                                    ushort* __restrict__ Wt) {
  int K = 1 << kshift;
  int t = blockIdx.x * 256 + threadIdx.x;
  if (t >= (K << 8)) return;
  int n = t >> kshift;
  int k = t & (K - 1);
  Wt[t] = f2bf(W[(size_t)k * 256 + n]);
}

// ---------- encoder: h0[n][j] = relu(x[n,:8] @ enc_w + enc_b), bf16 out ----------
__global__ __launch_bounds__(256) void encoder_kernel(const float* __restrict__ x,
                                                      const float* __restrict__ w,
                                                      const float* __restrict__ b,
                                                      ushort* __restrict__ h0) {
  int t = blockIdx.x * 256 + threadIdx.x;
  if (t >= NN * 64) return;
  int n = t >> 6, j = t & 63;
  float acc = b[j];
#pragma unroll
  for (int k = 0; k < 8; k++) acc += x[n * 8 + k] * w[k * 64 + j];
  h0[t] = f2bf(fmaxf(acc, 0.f));
}

// ---------- fused dual linear via MFMA: xl = A@Wl^T+bl ; xr = A@Wr^T+br ----------
__global__ __launch_bounds__(256) void dual_linear_mfma(const ushort* __restrict__ A, int K,
                                                        const ushort* __restrict__ Wl,
                                                        const ushort* __restrict__ Wr,
                                                        const float* __restrict__ bl,
                                                        const float* __restrict__ br,
                                                        ushort* __restrict__ xl,
                                                        ushort* __restrict__ xr) {
  int wave = threadIdx.x >> 6, lane = threadIdx.x & 63;
  int r0 = blockIdx.x * 32;
  int lr = lane & 15;        // row-in-frag (A) / col-in-frag (B/D)
  int kb = (lane >> 4) * 8;  // k-base within 32-wide k-step
  const ushort* W = (wave < 2) ? Wl : Wr;
  int wc0 = (wave & 1) * 128;
  f32x4 acc[2][8];
#pragma unroll
  for (int fr = 0; fr < 2; fr++)
#pragma unroll
    for (int fc = 0; fc < 8; fc++) acc[fr][fc] = (f32x4){0.f, 0.f, 0.f, 0.f};
  int rowA0 = min(r0 + 0 * 16 + lr, NN - 1);
  int rowA1 = min(r0 + 1 * 16 + lr, NN - 1);
  const ushort* pa0 = A + (size_t)rowA0 * K + kb;
  const ushort* pa1 = A + (size_t)rowA1 * K + kb;
  const ushort* pb = W + (size_t)(wc0 + lr) * K + kb;
  for (int k0 = 0; k0 < K; k0 += 32) {
    short8 a0 = *(const short8*)(pa0 + k0);
    short8 a1 = *(const short8*)(pa1 + k0);
    short8 b[8];
#pragma unroll
    for (int fc = 0; fc < 8; fc++) b[fc] = *(const short8*)(pb + (size_t)fc * 16 * K + k0);
#pragma unroll
    for (int fc = 0; fc < 8; fc++) {
      acc[0][fc] = __builtin_amdgcn_mfma_f32_16x16x32_bf16(a0, b[fc], acc[0][fc], 0, 0, 0);
      acc[1][fc] = __builtin_amdgcn_mfma_f32_16x16x32_bf16(a1, b[fc], acc[1][fc], 0, 0, 0);
    }
  }
  const float* bias = (wave < 2) ? bl : br;
  ushort* O = (wave < 2) ? xl : xr;
#pragma unroll
  for (int fc = 0; fc < 8; fc++) {
    int c = wc0 + fc * 16 + lr;
    float bv = bias[c];
#pragma unroll
    for (int fr = 0; fr < 2; fr++) {
#pragma unroll
      for (int j = 0; j < 4; j++) {
        int row = r0 + fr * 16 + (lane >> 4) * 4 + j;
        if (row < NN) O[(size_t)row * 256 + c] = f2bf(acc[fr][fc][j] + bv);
      }
    }
  }
}

// ================= counting sort of edges by dst =================
__global__ __launch_bounds__(256) void hist_kernel(const int* __restrict__ ei,
                                                   int* __restrict__ counts) {
  int t = blockIdx.x * 256 + threadIdx.x;
  for (int e = t; e < EP; e += gridDim.x * 256) {
    int dst = (e < NE) ? ei[NE + e] : e - NE;
    atomicAdd(&counts[dst], 1);
  }
}

__global__ __launch_bounds__(256) void scanA_kernel(const int* __restrict__ counts,
                                                    int* __restrict__ bsum) {
  int i = blockIdx.x * 256 + threadIdx.x;
  int v = (i < NN) ? counts[i] : 0;
  for (int off = 1; off < 64; off <<= 1) v += __shfl_xor(v, off, 64);
  __shared__ int sw[4];
  if ((threadIdx.x & 63) == 0) sw[threadIdx.x >> 6] = v;
  __syncthreads();
  if (threadIdx.x == 0) bsum[blockIdx.x] = sw[0] + sw[1] + sw[2] + sw[3];
}

__global__ void scanB_kernel(int* __restrict__ bsum) {
  if (threadIdx.x == 0 && blockIdx.x == 0) {
    int run = 0;
    for (int b = 0; b < NBLK_SCAN; b++) {
      int v = bsum[b];
      bsum[b] = run;
      run += v;
    }
  }
}

__global__ __launch_bounds__(256) void scanC_kernel(const int* __restrict__ counts,
                                                    const int* __restrict__ bpre,
                                                    int* __restrict__ offsets,
                                                    int* __restrict__ cursor) {
  __shared__ int s[256];
  int i = blockIdx.x * 256 + threadIdx.x;
  int v = (i < NN) ? counts[i] : 0;
  s[threadIdx.x] = v;
  __syncthreads();
  for (int off = 1; off < 256; off <<= 1) {
    int add = (threadIdx.x >= off) ? s[threadIdx.x - off] : 0;
    __syncthreads();
    s[threadIdx.x] += add;
    __syncthreads();
  }
  if (i < NN) {
    int excl = s[threadIdx.x] - v + bpre[blockIdx.x];
    offsets[i] = excl;
    cursor[i] = excl;
  }
}

__global__ __launch_bounds__(256) void scatter_kernel(const int* __restrict__ ei,
                                                      const float* __restrict__ ea,
                                                      const float* __restrict__ esum,
                                                      int* __restrict__ cursor,
                                                      int* __restrict__ ssrc,
                                                      float* __restrict__ sea) {
  int t = blockIdx.x * 256 + threadIdx.x;
  float mean = esum[0] * (1.0f / NE);
  for (int e = t; e < EP; e += gridDim.x * 256) {
    int src, dst;
    float v;
    if (e < NE) {
      src = ei[e];
      dst = ei[NE + e];
      v = ea[e];
    } else {
      src = dst = e - NE;
      v = mean;
    }
    int pos = atomicAdd(&cursor[dst], 1);
    ssrc[pos] = src;
    sea[pos] = v;
  }
}

// ================= degree-sort permutation (descending degree) =================
__global__ __launch_bounds__(256) void deg_hist_kernel(const int* __restrict__ counts,
                                                       int* __restrict__ dhist) {
  int i = blockIdx.x * 256 + threadIdx.x;
  if (i < NN) atomicAdd(&dhist[min(counts[i], 63)], 1);
}

__global__ void deg_scan_kernel(int* __restrict__ dhist) {
  if (threadIdx.x == 0 && blockIdx.x == 0) {
    int run = 0;
    for (int dc = 63; dc >= 0; --dc) {  // heavy degrees first
      int v = dhist[dc];
      dhist[dc] = run;
      run += v;
    }
  }
}

__global__ __launch_bounds__(256) void deg_scatter_kernel(const int* __restrict__ counts,
                                                          int* __restrict__ dhist,
                                                          int* __restrict__ perm) {
  int i = blockIdx.x * 256 + threadIdx.x;
  if (i < NN) {
    int pos = atomicAdd(&dhist[min(counts[i], 63)], 1);
    perm[pos] = i;
  }
}

// ================= fused GATv2 edge phase =================
// One wave per dst (degree-sorted). Lane l owns elems l*4..l*4+3 (head l>>4).
// leaky_relu(v) = 0.6v + 0.4|v| folded into att-dot; defer-max softmax (THR=8)
// -> commutative fast path, processed 2 edges/iter with 2-ahead prefetch.
__global__ __launch_bounds__(256) void gat_fused_kernel(const int* __restrict__ perm,
                                                        const int* __restrict__ offsets,
                                                        const int* __restrict__ counts,
                                                        const int* __restrict__ ssrc,
                                                        const float* __restrict__ sea,
                                                        const ushort* __restrict__ xl,
                                                        const ushort* __restrict__ xr,
                                                        const float* __restrict__ we,
                                                        const float* __restrict__ att,
                                                        const float* __restrict__ bias,
                                                        ushort* __restrict__ hb) {
  int w = threadIdx.x >> 6, lane = threadIdx.x & 63;
  int bi = blockIdx.x * 4 + w;
  if (bi >= NN) return;
  int d = perm[bi];
  int off = offsets[d], cnt = counts[d];
  const int c4 = lane * 4;
  ushort4 xru = *(const ushort4*)(xr + (size_t)d * 256 + c4);
  const float4 xr4 = {bf2f(xru.x), bf2f(xru.y), bf2f(xru.z), bf2f(xru.w)};
  const float4 we4 = *(const float4*)(we + c4);
  const float4 at4 = *(const float4*)(att + c4);
  const float4 a06 = {0.6f * at4.x, 0.6f * at4.y, 0.6f * at4.z, 0.6f * at4.w};
  const float4 a04 = {0.4f * at4.x, 0.4f * at4.y, 0.4f * at4.z, 0.4f * at4.w};
  float4 acc = {0.f, 0.f, 0.f, 0.f};
  float den = 0.f, m = -1e30f;
  // pipeline registers (pair i, pair i+2 prefetched)
  ushort4 xu0 = {0, 0, 0, 0}, xu1 = {0, 0, 0, 0};
  float ea0 = 0.f, ea1 = 0.f;
  xu0 = *(const ushort4*)(xl + (size_t)ssrc[off] * 256 + c4);
  ea0 = sea[off];
  if (1 < cnt) {
    xu1 = *(const ushort4*)(xl + (size_t)ssrc[off + 1] * 256 + c4);
    ea1 = sea[off + 1];
  }
  for (int i = 0; i < cnt; i += 2) {
    ushort4 cx0 = xu0, cx1 = xu1;
    float ce0 = ea0, ce1 = ea1;
    bool e1v = (i + 1) < cnt;
    if (i + 2 < cnt) {  // prefetch next pair
      xu0 = *(const ushort4*)(xl + (size_t)ssrc[off + i + 2] * 256 + c4);
      ea0 = sea[off + i + 2];
      if (i + 3 < cnt) {
        xu1 = *(const ushort4*)(xl + (size_t)ssrc[off + i + 3] * 256 + c4);
        ea1 = sea[off + i + 3];
      }
    }
    float4 xf0 = {bf2f(cx0.x), bf2f(cx0.y), bf2f(cx0.z), bf2f(cx0.w)};
    float4 xf1 = {bf2f(cx1.x), bf2f(cx1.y), bf2f(cx1.z), bf2f(cx1.w)};
    float v00 = xf0.x + fmaf(ce0, we4.x, xr4.x);
    float v01 = xf0.y + fmaf(ce0, we4.y, xr4.y);
    float v02 = xf0.z + fmaf(ce0, we4.z, xr4.z);
    float v03 = xf0.w + fmaf(ce0, we4.w, xr4.w);
    float v10 = xf1.x + fmaf(ce1, we4.x, xr4.x);
    float v11 = xf1.y + fmaf(ce1, we4.y, xr4.y);
    float v12 = xf1.z + fmaf(ce1, we4.z, xr4.z);
    float v13 = xf1.w + fmaf(ce1, we4.w, xr4.w);
    float p0 = fmaf(a06.x, v00, a04.x * fabsf(v00));
    p0 = fmaf(a06.y, v01, fmaf(a04.y, fabsf(v01), p0));
    p0 = fmaf(a06.z, v02, fmaf(a04.z, fabsf(v02), p0));
    p0 = fmaf(a06.w, v03, fmaf(a04.w, fabsf(v03), p0));
    float p1 = fmaf(a06.x, v10, a04.x * fabsf(v10));
    p1 = fmaf(a06.y, v11, fmaf(a04.y, fabsf(v11), p1));
    p1 = fmaf(a06.z, v12, fmaf(a04.z, fabsf(v12), p1));
    p1 = fmaf(a06.w, v13, fmaf(a04.w, fabsf(v13), p1));
    p0 += __shfl_xor(p0, 1, 64);
    p0 += __shfl_xor(p0, 2, 64);
    p0 += __shfl_xor(p0, 4, 64);
    p0 += __shfl_xor(p0, 8, 64);
    p1 += __shfl_xor(p1, 1, 64);
    p1 += __shfl_xor(p1, 2, 64);
    p1 += __shfl_xor(p1, 4, 64);
    p1 += __shfl_xor(p1, 8, 64);
    float thrm = m + DEFER_THR;
    if (__all((p0 <= thrm) && (!e1v || p1 <= thrm))) {
      // fast path: m unchanged, commutative accumulation
      float ex0 = __expf(p0 - m);
      float ex1 = e1v ? __expf(p1 - m) : 0.f;
      den += ex0 + ex1;
      acc.x = fmaf(xf0.x, ex0, fmaf(xf1.x, ex1, acc.x));
      acc.y = fmaf(xf0.y, ex0, fmaf(xf1.y, ex1, acc.y));
      acc.z = fmaf(xf0.z, ex0, fmaf(xf1.z, ex1, acc.z));
      acc.w = fmaf(xf0.w, ex0, fmaf(xf1.w, ex1, acc.w));
    } else {
      // slow path: full online update per edge
      {
        float mn = fmaxf(m, p0);
        float sc = __expf(m - mn);
        float ex = __expf(p0 - mn);
        den = fmaf(den, sc, ex);
        acc.x = fmaf(acc.x, sc, xf0.x * ex);
        acc.y = fmaf(acc.y, sc, xf0.y * ex);
        acc.z = fmaf(acc.z, sc, xf0.z * ex);
        acc.w = fmaf(acc.w, sc, xf0.w * ex);
        m = mn;
      }
      if (e1v) {
        float mn = fmaxf(m, p1);
        float sc = __expf(m - mn);
        float ex = __expf(p1 - mn);
        den = fmaf(den, sc, ex);
        acc.x = fmaf(acc.x, sc, xf1.x * ex);
        acc.y = fmaf(acc.y, sc, xf1.y * ex);
        acc.z = fmaf(acc.z, sc, xf1.z * ex);
        acc.w = fmaf(acc.w, sc, xf1.w * ex);
        m = mn;
      }
    }
  }
  const float4 b4 = *(const float4*)(bias + c4);
  float inv = 1.f / den;  // every node has a self-loop -> den > 0
  ushort4 o;
  o.x = f2bf(fmaxf(fmaf(acc.x, inv, b4.x), 0.f));
  o.y = f2bf(fmaxf(fmaf(acc.y, inv, b4.y), 0.f));
  o.z = f2bf(fmaxf(fmaf(acc.z, inv, b4.z), 0.f));
  o.w = f2bf(fmaxf(fmaf(acc.w, inv, b4.w), 0.f));
  *(ushort4*)(hb + (size_t)d * 256 + c4) = o;
}

// ---------- global mean pool (batch is sorted; run-length flush) ----------
__global__ __launch_bounds__(256) void pool_kernel(const ushort* __restrict__ h,
                                                   const int* __restrict__ batch,
                                                   float* __restrict__ sums,
                                                   float* __restrict__ cnts) {
  __shared__ int sb[128];
  int n0 = blockIdx.x * 128;
  int j = threadIdx.x;
  int count = min(128, NN - n0);
  if (count <= 0) return;
  for (int t = threadIdx.x; t < count; t += 256) sb[t] = batch[n0 + t];
  __syncthreads();
  float acc = 0.f;
  int run = 0;
  int cur = sb[0];
  for (int i = 0; i < count; ++i) {
    int b = sb[i];
    if (b != cur) {
      atomicAdd(&sums[(size_t)cur * 256 + j], acc);
      if (j == 0) atomicAdd(&cnts[cur], (float)run);
      acc = 0.f;
      run = 0;
      cur = b;
    }
    acc += bf2f(h[(size_t)(n0 + i) * 256 + j]);
    run++;
  }
  atomicAdd(&sums[(size_t)cur * 256 + j], acc);
  if (j == 0) atomicAdd(&cnts[cur], (float)run);
}

// ---------- post-MLP head: one block per graph ----------
__global__ __launch_bounds__(128) void head_kernel(const float* __restrict__ sums,
                                                   const float* __restrict__ cnts,
                                                   const float* __restrict__ p1_w,
                                                   const float* __restrict__ p1_b,
                                                   const float* __restrict__ ln_g,
                                                   const float* __restrict__ ln_b,
                                                   const float* __restrict__ p2_w,
                                                   const float* __restrict__ p2_b,
                                                   const float* __restrict__ hc_w,
                                                   const float* __restrict__ hc_b,
                                                   const float* __restrict__ hf_w,
                                                   const float* __restrict__ hf_b,
                                                   float* __restrict__ out) {
  int g = blockIdx.x;
  int j = threadIdx.x;  // 0..127
  __shared__ float sp[256], st[128], sz[64];
  float cnt = fmaxf(cnts[g], 1.0f);
  for (int t = j; t < 256; t += 128) sp[t] = sums[(size_t)g * 256 + t] / cnt;
  __syncthreads();
  float acc = p1_b[j];
  for (int k = 0; k < 256; k++) acc += sp[k] * p1_w[(size_t)k * 128 + j];
  st[j] = acc;
  __syncthreads();
  float mu = 0.f;
  for (int k = 0; k < 128; k++) mu += st[k];
  mu *= (1.f / 128.f);
  float var = 0.f;
  for (int k = 0; k < 128; k++) {
    float d = st[k] - mu;
    var += d * d;
  }
  var *= (1.f / 128.f);
  float tj = (acc - mu) * rsqrtf(var + 1e-5f) * ln_g[j] + ln_b[j];
  tj = fmaxf(tj, 0.f);
  __syncthreads();
  st[j] = tj;
  __syncthreads();
  if (j < 64) {
    float z = p2_b[j];
    for (int k = 0; k < 128; k++) z += st[k] * p2_w[(size_t)k * 64 + j];
    z = fmaxf(z, 0.f);
    sz[j] = z;
    out[500 + (size_t)g * 64 + j] = z;  // output 2: z [B,64]
  }
  __syncthreads();
  if (j == 0) {
    float c = hc_b[0];
    for (int k = 0; k < 64; k++) c += sz[k] * hc_w[k];
    out[g] = c;  // output 0: cooling [B]
  }
  if (j >= 1 && j < 10) {
    int f = j - 1;
    float v = hf_b[f];
    for (int k = 0; k < 64; k++) v += sz[k] * hf_w[(size_t)k * 9 + f];
    out[50 + (size_t)g * 9 + f] = v;  // output 1: fatigue [B,9]
  }
}

extern "C" void kernel_launch(void* const* d_in, const int* in_sizes, int n_in,
                              void* d_out, int out_size, void* d_ws, size_t ws_size,
                              hipStream_t stream) {
  const float* x = (const float*)d_in[0];
  const int* ei = (const int*)d_in[1];
  const float* ea = (const float*)d_in[2];
  const int* batch = (const int*)d_in[3];
  const float* enc_w = (const float*)d_in[4];
  const float* enc_b = (const float*)d_in[5];
  const float* g1_wl = (const float*)d_in[6];
  const float* g1_bl = (const float*)d_in[7];
  const float* g1_wr = (const float*)d_in[8];
  const float* g1_br = (const float*)d_in[9];
  const float* g1_we = (const float*)d_in[10];
  const float* g1_att = (const float*)d_in[11];
  const float* g1_bias = (const float*)d_in[12];
  const float* g2_wl = (const float*)d_in[13];
  const float* g2_bl = (const float*)d_in[14];
  const float* g2_wr = (const float*)d_in[15];
  const float* g2_br = (const float*)d_in[16];
  const float* g2_we = (const float*)d_in[17];
  const float* g2_att = (const float*)d_in[18];
  const float* g2_bias = (const float*)d_in[19];
  const float* p1_w = (const float*)d_in[20];
  const float* p1_b = (const float*)d_in[21];
  const float* ln_g = (const float*)d_in[22];
  const float* ln_b = (const float*)d_in[23];
  const float* p2_w = (const float*)d_in[24];
  const float* p2_b = (const float*)d_in[25];
  const float* hc_w = (const float*)d_in[26];
  const float* hc_b = (const float*)d_in[27];
  const float* hf_w = (const float*)d_in[28];
  const float* hf_b = (const float*)d_in[29];
  float* out = (float*)d_out;

  // ---- workspace layout ----
  ushort* xlb = (ushort*)d_ws;               // N*256 bf16
  ushort* xrb = xlb + (size_t)NN * 256;      // N*256 bf16
  ushort* hb = xrb + (size_t)NN * 256;       // N*256 bf16
  ushort* h0b = hb + (size_t)NN * 256;       // N*64 bf16
  ushort* w1l = h0b + (size_t)NN * 64;       // 256*64 bf16 (transposed)
  ushort* w1r = w1l + 256 * 64;
  ushort* w2l = w1r + 256 * 64;              // 256*256 bf16
  ushort* w2r = w2l + 256 * 256;
  float* sea = (float*)(w2r + 256 * 256);    // EP
  int* ssrc = (int*)(sea + EP);              // EP
  int* counts = ssrc + EP;                   // NN
  int* offsets = counts + NN;                // NN
  int* cursor = offsets + NN;                // NN
  int* perm = cursor + NN;                   // NN
  int* bsum = perm + NN;                     // NBLK_SCAN
  int* dhist = bsum + NBLK_SCAN;             // 64
  float* sums = (float*)(dhist + 64);        // B*256
  float* cnts = sums + (size_t)NB * 256;     // B
  float* esum = cnts + NB;                   // 1

  // ---- edge_attr mean ----
  hipMemsetAsync(esum, 0, sizeof(float), stream);
  reduce_sum_kernel<<<256, 256, 0, stream>>>(ea, esum);

  // ---- counting sort of edges by dst (graph static: reused by both layers) ----
  hipMemsetAsync(counts, 0, (size_t)NN * sizeof(int), stream);
  hist_kernel<<<1024, 256, 0, stream>>>(ei, counts);
  scanA_kernel<<<NBLK_SCAN, 256, 0, stream>>>(counts, bsum);
  scanB_kernel<<<1, 64, 0, stream>>>(bsum);
  scanC_kernel<<<NBLK_SCAN, 256, 0, stream>>>(counts, bsum, offsets, cursor);
  scatter_kernel<<<1024, 256, 0, stream>>>(ei, ea, esum, cursor, ssrc, sea);

  // ---- degree-sorted dst permutation (heavy first; balances block waves) ----
  hipMemsetAsync(dhist, 0, 64 * sizeof(int), stream);
  deg_hist_kernel<<<NBLK_SCAN, 256, 0, stream>>>(counts, dhist);
  deg_scan_kernel<<<1, 64, 0, stream>>>(dhist);
  deg_scatter_kernel<<<NBLK_SCAN, 256, 0, stream>>>(counts, dhist, perm);

  // ---- weight conversion (f32 [K][256] -> bf16 [256][K]) ----
  wconv_kernel<<<64, 256, 0, stream>>>(g1_wl, 6, w1l);
  wconv_kernel<<<64, 256, 0, stream>>>(g1_wr, 6, w1r);
  wconv_kernel<<<256, 256, 0, stream>>>(g2_wl, 8, w2l);
  wconv_kernel<<<256, 256, 0, stream>>>(g2_wr, 8, w2r);

  // ---- encoder ----
  encoder_kernel<<<(NN * 64 + 255) / 256, 256, 0, stream>>>(x, enc_w, enc_b, h0b);

  const int nGemmBlocks = (NN + 31) / 32;
  const int nGatBlocks = (NN + 3) / 4;

  // ================= GAT layer 1 (K=64) =================
  dual_linear_mfma<<<nGemmBlocks, 256, 0, stream>>>(h0b, 64, w1l, w1r, g1_bl, g1_br, xlb, xrb);
  gat_fused_kernel<<<nGatBlocks, 256, 0, stream>>>(perm, offsets, counts, ssrc, sea, xlb, xrb,
                                                   g1_we, g1_att, g1_bias, hb);

  // ================= GAT layer 2 (K=256) =================
  dual_linear_mfma<<<nGemmBlocks, 256, 0, stream>>>(hb, 256, w2l, w2r, g2_bl, g2_br, xlb, xrb);
  gat_fused_kernel<<<nGatBlocks, 256, 0, stream>>>(perm, offsets, counts, ssrc, sea, xlb, xrb,
                                                   g2_we, g2_att, g2_bias, hb);

  // ================= pool + head =================
  hipMemsetAsync(sums, 0, (size_t)NB * 256 * sizeof(float), stream);
  hipMemsetAsync(cnts, 0, (size_t)NB * sizeof(float), stream);
  pool_kernel<<<(NN + 127) / 128, 256, 0, stream>>>(hb, batch, sums, cnts);
  head_kernel<<<NB, 128, 0, stream>>>(sums, cnts, p1_w, p1_b, ln_g, ln_b, p2_w, p2_b,
                                      hc_w, hc_b, hf_w, hf_b, out);
}

// Round 6
// 418.761 us; speedup vs baseline: 1.7355x; 1.7355x over previous
//
#include <hip/hip_runtime.h>
#include <hip/hip_bf16.h>

#define NN 50000      // nodes
#define NE 500000     // edges (without self loops)
#define EP (NE + NN)  // edges with self loops
#define NB 50         // graphs
#define NEG 0.2f
#define NBLK_SCAN 196  // ceil(NN/256)
#define DEFER_THR 8.0f

typedef __attribute__((ext_vector_type(8))) short short8;
typedef __attribute__((ext_vector_type(4))) float f32x4;

__device__ __forceinline__ ushort f2bf(float f) {
  unsigned u = __float_as_uint(f);
  unsigned r = (u + 0x7FFFu + ((u >> 16) & 1u)) >> 16;
  return (ushort)r;
}
__device__ __forceinline__ float bf2f(ushort b) {
  return __uint_as_float(((unsigned)b) << 16);
}

// ---------- mean(edge_attr) : sum into esum[0] ----------
__global__ __launch_bounds__(256) void reduce_sum_kernel(const float* __restrict__ ea,
                                                         float* __restrict__ esum) {
  int t = blockIdx.x * 256 + threadIdx.x;
  float v = 0.f;
  for (int i = t; i < NE; i += gridDim.x * 256) v += ea[i];
  for (int off = 1; off < 64; off <<= 1) v += __shfl_xor(v, off, 64);
  if ((threadIdx.x & 63) == 0) atomicAdd(esum, v);
}

// ---------- weight convert+transpose: W[K][256] f32 -> Wt[256][K] bf16 ----------
__global__ __launch_bounds__(256) void wconv_kernel(const float* __restrict__ W,
                                                    int kshift,  // log2(K)
                                                    ushort* __restrict__ Wt) {
  int K = 1 << kshift;
  int t = blockIdx.x * 256 + threadIdx.x;
  if (t >= (K << 8)) return;
  int n = t >> kshift;
  int k = t & (K - 1);
  Wt[t] = f2bf(W[(size_t)k * 256 + n]);
}

// ---------- encoder: h0[n][j] = relu(x[n,:8] @ enc_w + enc_b), bf16 out ----------
__global__ __launch_bounds__(256) void encoder_kernel(const float* __restrict__ x,
                                                      const float* __restrict__ w,
                                                      const float* __restrict__ b,
                                                      ushort* __restrict__ h0) {
  int t = blockIdx.x * 256 + threadIdx.x;
  if (t >= NN * 64) return;
  int n = t >> 6, j = t & 63;
  float acc = b[j];
#pragma unroll
  for (int k = 0; k < 8; k++) acc += x[n * 8 + k] * w[k * 64 + j];
  h0[t] = f2bf(fmaxf(acc, 0.f));
}

// ---------- fused dual linear via MFMA: xl = A@Wl^T+bl ; xr = A@Wr^T+br ----------
__global__ __launch_bounds__(256) void dual_linear_mfma(const ushort* __restrict__ A, int K,
                                                        const ushort* __restrict__ Wl,
                                                        const ushort* __restrict__ Wr,
                                                        const float* __restrict__ bl,
                                                        const float* __restrict__ br,
                                                        ushort* __restrict__ xl,
                                                        ushort* __restrict__ xr) {
  int wave = threadIdx.x >> 6, lane = threadIdx.x & 63;
  int r0 = blockIdx.x * 32;
  int lr = lane & 15;        // row-in-frag (A) / col-in-frag (B/D)
  int kb = (lane >> 4) * 8;  // k-base within 32-wide k-step
  const ushort* W = (wave < 2) ? Wl : Wr;
  int wc0 = (wave & 1) * 128;
  f32x4 acc[2][8];
#pragma unroll
  for (int fr = 0; fr < 2; fr++)
#pragma unroll
    for (int fc = 0; fc < 8; fc++) acc[fr][fc] = (f32x4){0.f, 0.f, 0.f, 0.f};
  int rowA0 = min(r0 + 0 * 16 + lr, NN - 1);
  int rowA1 = min(r0 + 1 * 16 + lr, NN - 1);
  const ushort* pa0 = A + (size_t)rowA0 * K + kb;
  const ushort* pa1 = A + (size_t)rowA1 * K + kb;
  const ushort* pb = W + (size_t)(wc0 + lr) * K + kb;
  for (int k0 = 0; k0 < K; k0 += 32) {
    short8 a0 = *(const short8*)(pa0 + k0);
    short8 a1 = *(const short8*)(pa1 + k0);
    short8 b[8];
#pragma unroll
    for (int fc = 0; fc < 8; fc++) b[fc] = *(const short8*)(pb + (size_t)fc * 16 * K + k0);
#pragma unroll
    for (int fc = 0; fc < 8; fc++) {
      acc[0][fc] = __builtin_amdgcn_mfma_f32_16x16x32_bf16(a0, b[fc], acc[0][fc], 0, 0, 0);
      acc[1][fc] = __builtin_amdgcn_mfma_f32_16x16x32_bf16(a1, b[fc], acc[1][fc], 0, 0, 0);
    }
  }
  const float* bias = (wave < 2) ? bl : br;
  ushort* O = (wave < 2) ? xl : xr;
#pragma unroll
  for (int fc = 0; fc < 8; fc++) {
    int c = wc0 + fc * 16 + lr;
    float bv = bias[c];
#pragma unroll
    for (int fr = 0; fr < 2; fr++) {
#pragma unroll
      for (int j = 0; j < 4; j++) {
        int row = r0 + fr * 16 + (lane >> 4) * 4 + j;
        if (row < NN) O[(size_t)row * 256 + c] = f2bf(acc[fr][fc][j] + bv);
      }
    }
  }
}

// ================= counting sort of edges by dst =================
__global__ __launch_bounds__(256) void hist_kernel(const int* __restrict__ ei,
                                                   int* __restrict__ counts) {
  int t = blockIdx.x * 256 + threadIdx.x;
  for (int e = t; e < EP; e += gridDim.x * 256) {
    int dst = (e < NE) ? ei[NE + e] : e - NE;
    atomicAdd(&counts[dst], 1);
  }
}

__global__ __launch_bounds__(256) void scanA_kernel(const int* __restrict__ counts,
                                                    int* __restrict__ bsum) {
  int i = blockIdx.x * 256 + threadIdx.x;
  int v = (i < NN) ? counts[i] : 0;
  for (int off = 1; off < 64; off <<= 1) v += __shfl_xor(v, off, 64);
  __shared__ int sw[4];
  if ((threadIdx.x & 63) == 0) sw[threadIdx.x >> 6] = v;
  __syncthreads();
  if (threadIdx.x == 0) bsum[blockIdx.x] = sw[0] + sw[1] + sw[2] + sw[3];
}

__global__ void scanB_kernel(int* __restrict__ bsum) {
  if (threadIdx.x == 0 && blockIdx.x == 0) {
    int run = 0;
    for (int b = 0; b < NBLK_SCAN; b++) {
      int v = bsum[b];
      bsum[b] = run;
      run += v;
    }
  }
}

__global__ __launch_bounds__(256) void scanC_kernel(const int* __restrict__ counts,
                                                    const int* __restrict__ bpre,
                                                    int* __restrict__ offsets,
                                                    int* __restrict__ cursor) {
  __shared__ int s[256];
  int i = blockIdx.x * 256 + threadIdx.x;
  int v = (i < NN) ? counts[i] : 0;
  s[threadIdx.x] = v;
  __syncthreads();
  for (int off = 1; off < 256; off <<= 1) {
    int add = (threadIdx.x >= off) ? s[threadIdx.x - off] : 0;
    __syncthreads();
    s[threadIdx.x] += add;
    __syncthreads();
  }
  if (i < NN) {
    int excl = s[threadIdx.x] - v + bpre[blockIdx.x];
    offsets[i] = excl;
    cursor[i] = excl;
  }
}

// scatter packed (src, edge_attr) per edge, bucketed by dst
__global__ __launch_bounds__(256) void scatter_kernel(const int* __restrict__ ei,
                                                      const float* __restrict__ ea,
                                                      const float* __restrict__ esum,
                                                      int* __restrict__ cursor,
                                                      int2* __restrict__ sedge) {
  int t = blockIdx.x * 256 + threadIdx.x;
  float mean = esum[0] * (1.0f / NE);
  for (int e = t; e < EP; e += gridDim.x * 256) {
    int src, dst;
    float v;
    if (e < NE) {
      src = ei[e];
      dst = ei[NE + e];
      v = ea[e];
    } else {
      src = dst = e - NE;
      v = mean;
    }
    int pos = atomicAdd(&cursor[dst], 1);
    sedge[pos] = make_int2(src, __float_as_int(v));
  }
}

// ================= fused GATv2 edge phase =================
// One wave per dst. Lane l owns elems l*4..l*4+3 (head l>>4).
// leaky_relu(v) = 0.6v + 0.4|v| folded into att-dot; defer-max softmax (THR=8)
// -> commutative fast path, 2 edges/iter with 2-ahead prefetch; packed int2 edges.
__global__ __launch_bounds__(256) void gat_fused_kernel(const int* __restrict__ offsets,
                                                        const int* __restrict__ counts,
                                                        const int2* __restrict__ sedge,
                                                        const ushort* __restrict__ xl,
                                                        const ushort* __restrict__ xr,
                                                        const float* __restrict__ we,
                                                        const float* __restrict__ att,
                                                        const float* __restrict__ bias,
                                                        ushort* __restrict__ hb) {
  int w = threadIdx.x >> 6, lane = threadIdx.x & 63;
  int d = blockIdx.x * 4 + w;
  if (d >= NN) return;
  int off = offsets[d], cnt = counts[d];
  const int c4 = lane * 4;
  ushort4 xru = *(const ushort4*)(xr + (size_t)d * 256 + c4);
  const float4 xr4 = {bf2f(xru.x), bf2f(xru.y), bf2f(xru.z), bf2f(xru.w)};
  const float4 we4 = *(const float4*)(we + c4);
  const float4 at4 = *(const float4*)(att + c4);
  const float4 a06 = {0.6f * at4.x, 0.6f * at4.y, 0.6f * at4.z, 0.6f * at4.w};
  const float4 a04 = {0.4f * at4.x, 0.4f * at4.y, 0.4f * at4.z, 0.4f * at4.w};
  float4 acc = {0.f, 0.f, 0.f, 0.f};
  float den = 0.f, m = -1e30f;
  const int2* pe = sedge + off;
  // pipeline registers (pair i, pair i+2 prefetched)
  ushort4 xu0 = {0, 0, 0, 0}, xu1 = {0, 0, 0, 0};
  float ea0 = 0.f, ea1 = 0.f;
  {
    int2 e0 = pe[0];
    xu0 = *(const ushort4*)(xl + (size_t)e0.x * 256 + c4);
    ea0 = __int_as_float(e0.y);
    if (1 < cnt) {
      int2 e1 = pe[1];
      xu1 = *(const ushort4*)(xl + (size_t)e1.x * 256 + c4);
      ea1 = __int_as_float(e1.y);
    }
  }
  for (int i = 0; i < cnt; i += 2) {
    ushort4 cx0 = xu0, cx1 = xu1;
    float ce0 = ea0, ce1 = ea1;
    bool e1v = (i + 1) < cnt;
    if (i + 2 < cnt) {  // prefetch next pair
      int2 e0 = pe[i + 2];
      xu0 = *(const ushort4*)(xl + (size_t)e0.x * 256 + c4);
      ea0 = __int_as_float(e0.y);
      if (i + 3 < cnt) {
        int2 e1 = pe[i + 3];
        xu1 = *(const ushort4*)(xl + (size_t)e1.x * 256 + c4);
        ea1 = __int_as_float(e1.y);
      }
    }
    float4 xf0 = {bf2f(cx0.x), bf2f(cx0.y), bf2f(cx0.z), bf2f(cx0.w)};
    float4 xf1 = {bf2f(cx1.x), bf2f(cx1.y), bf2f(cx1.z), bf2f(cx1.w)};
    float v00 = xf0.x + fmaf(ce0, we4.x, xr4.x);
    float v01 = xf0.y + fmaf(ce0, we4.y, xr4.y);
    float v02 = xf0.z + fmaf(ce0, we4.z, xr4.z);
    float v03 = xf0.w + fmaf(ce0, we4.w, xr4.w);
    float v10 = xf1.x + fmaf(ce1, we4.x, xr4.x);
    float v11 = xf1.y + fmaf(ce1, we4.y, xr4.y);
    float v12 = xf1.z + fmaf(ce1, we4.z, xr4.z);
    float v13 = xf1.w + fmaf(ce1, we4.w, xr4.w);
    float p0 = fmaf(a06.x, v00, a04.x * fabsf(v00));
    p0 = fmaf(a06.y, v01, fmaf(a04.y, fabsf(v01), p0));
    p0 = fmaf(a06.z, v02, fmaf(a04.z, fabsf(v02), p0));
    p0 = fmaf(a06.w, v03, fmaf(a04.w, fabsf(v03), p0));
    float p1 = fmaf(a06.x, v10, a04.x * fabsf(v10));
    p1 = fmaf(a06.y, v11, fmaf(a04.y, fabsf(v11), p1));
    p1 = fmaf(a06.z, v12, fmaf(a04.z, fabsf(v12), p1));
    p1 = fmaf(a06.w, v13, fmaf(a04.w, fabsf(v13), p1));
    p0 += __shfl_xor(p0, 1, 64);
    p0 += __shfl_xor(p0, 2, 64);
    p0 += __shfl_xor(p0, 4, 64);
    p0 += __shfl_xor(p0, 8, 64);
    p1 += __shfl_xor(p1, 1, 64);
    p1 += __shfl_xor(p1, 2, 64);
    p1 += __shfl_xor(p1, 4, 64);
    p1 += __shfl_xor(p1, 8, 64);
    float thrm = m + DEFER_THR;
    if (__all((p0 <= thrm) && (!e1v || p1 <= thrm))) {
      // fast path: m unchanged, commutative accumulation
      float ex0 = __expf(p0 - m);
      float ex1 = e1v ? __expf(p1 - m) : 0.f;
      den += ex0 + ex1;
      acc.x = fmaf(xf0.x, ex0, fmaf(xf1.x, ex1, acc.x));
      acc.y = fmaf(xf0.y, ex0, fmaf(xf1.y, ex1, acc.y));
      acc.z = fmaf(xf0.z, ex0, fmaf(xf1.z, ex1, acc.z));
      acc.w = fmaf(xf0.w, ex0, fmaf(xf1.w, ex1, acc.w));
    } else {
      // slow path: full online update per edge
      {
        float mn = fmaxf(m, p0);
        float sc = __expf(m - mn);
        float ex = __expf(p0 - mn);
        den = fmaf(den, sc, ex);
        acc.x = fmaf(acc.x, sc, xf0.x * ex);
        acc.y = fmaf(acc.y, sc, xf0.y * ex);
        acc.z = fmaf(acc.z, sc, xf0.z * ex);
        acc.w = fmaf(acc.w, sc, xf0.w * ex);
        m = mn;
      }
      if (e1v) {
        float mn = fmaxf(m, p1);
        float sc = __expf(m - mn);
        float ex = __expf(p1 - mn);
        den = fmaf(den, sc, ex);
        acc.x = fmaf(acc.x, sc, xf1.x * ex);
        acc.y = fmaf(acc.y, sc, xf1.y * ex);
        acc.z = fmaf(acc.z, sc, xf1.z * ex);
        acc.w = fmaf(acc.w, sc, xf1.w * ex);
        m = mn;
      }
    }
  }
  const float4 b4 = *(const float4*)(bias + c4);
  float inv = 1.f / den;  // every node has a self-loop -> den > 0
  ushort4 o;
  o.x = f2bf(fmaxf(fmaf(acc.x, inv, b4.x), 0.f));
  o.y = f2bf(fmaxf(fmaf(acc.y, inv, b4.y), 0.f));
  o.z = f2bf(fmaxf(fmaf(acc.z, inv, b4.z), 0.f));
  o.w = f2bf(fmaxf(fmaf(acc.w, inv, b4.w), 0.f));
  *(ushort4*)(hb + (size_t)d * 256 + c4) = o;
}

// ---------- global mean pool (batch is sorted; run-length flush) ----------
__global__ __launch_bounds__(256) void pool_kernel(const ushort* __restrict__ h,
                                                   const int* __restrict__ batch,
                                                   float* __restrict__ sums,
                                                   float* __restrict__ cnts) {
  __shared__ int sb[128];
  int n0 = blockIdx.x * 128;
  int j = threadIdx.x;
  int count = min(128, NN - n0);
  if (count <= 0) return;
  for (int t = threadIdx.x; t < count; t += 256) sb[t] = batch[n0 + t];
  __syncthreads();
  float acc = 0.f;
  int run = 0;
  int cur = sb[0];
  for (int i = 0; i < count; ++i) {
    int b = sb[i];
    if (b != cur) {
      atomicAdd(&sums[(size_t)cur * 256 + j], acc);
      if (j == 0) atomicAdd(&cnts[cur], (float)run);
      acc = 0.f;
      run = 0;
      cur = b;
    }
    acc += bf2f(h[(size_t)(n0 + i) * 256 + j]);
    run++;
  }
  atomicAdd(&sums[(size_t)cur * 256 + j], acc);
  if (j == 0) atomicAdd(&cnts[cur], (float)run);
}

// ---------- post-MLP head: one block per graph ----------
__global__ __launch_bounds__(128) void head_kernel(const float* __restrict__ sums,
                                                   const float* __restrict__ cnts,
                                                   const float* __restrict__ p1_w,
                                                   const float* __restrict__ p1_b,
                                                   const float* __restrict__ ln_g,
                                                   const float* __restrict__ ln_b,
                                                   const float* __restrict__ p2_w,
                                                   const float* __restrict__ p2_b,
                                                   const float* __restrict__ hc_w,
                                                   const float* __restrict__ hc_b,
                                                   const float* __restrict__ hf_w,
                                                   const float* __restrict__ hf_b,
                                                   float* __restrict__ out) {
  int g = blockIdx.x;
  int j = threadIdx.x;  // 0..127
  __shared__ float sp[256], st[128], sz[64];
  float cnt = fmaxf(cnts[g], 1.0f);
  for (int t = j; t < 256; t += 128) sp[t] = sums[(size_t)g * 256 + t] / cnt;
  __syncthreads();
  float acc = p1_b[j];
  for (int k = 0; k < 256; k++) acc += sp[k] * p1_w[(size_t)k * 128 + j];
  st[j] = acc;
  __syncthreads();
  float mu = 0.f;
  for (int k = 0; k < 128; k++) mu += st[k];
  mu *= (1.f / 128.f);
  float var = 0.f;
  for (int k = 0; k < 128; k++) {
    float d = st[k] - mu;
    var += d * d;
  }
  var *= (1.f / 128.f);
  float tj = (acc - mu) * rsqrtf(var + 1e-5f) * ln_g[j] + ln_b[j];
  tj = fmaxf(tj, 0.f);
  __syncthreads();
  st[j] = tj;
  __syncthreads();
  if (j < 64) {
    float z = p2_b[j];
    for (int k = 0; k < 128; k++) z += st[k] * p2_w[(size_t)k * 64 + j];
    z = fmaxf(z, 0.f);
    sz[j] = z;
    out[500 + (size_t)g * 64 + j] = z;  // output 2: z [B,64]
  }
  __syncthreads();
  if (j == 0) {
    float c = hc_b[0];
    for (int k = 0; k < 64; k++) c += sz[k] * hc_w[k];
    out[g] = c;  // output 0: cooling [B]
  }
  if (j >= 1 && j < 10) {
    int f = j - 1;
    float v = hf_b[f];
    for (int k = 0; k < 64; k++) v += sz[k] * hf_w[(size_t)k * 9 + f];
    out[50 + (size_t)g * 9 + f] = v;  // output 1: fatigue [B,9]
  }
}

extern "C" void kernel_launch(void* const* d_in, const int* in_sizes, int n_in,
                              void* d_out, int out_size, void* d_ws, size_t ws_size,
                              hipStream_t stream) {
  const float* x = (const float*)d_in[0];
  const int* ei = (const int*)d_in[1];
  const float* ea = (const float*)d_in[2];
  const int* batch = (const int*)d_in[3];
  const float* enc_w = (const float*)d_in[4];
  const float* enc_b = (const float*)d_in[5];
  const float* g1_wl = (const float*)d_in[6];
  const float* g1_bl = (const float*)d_in[7];
  const float* g1_wr = (const float*)d_in[8];
  const float* g1_br = (const float*)d_in[9];
  const float* g1_we = (const float*)d_in[10];
  const float* g1_att = (const float*)d_in[11];
  const float* g1_bias = (const float*)d_in[12];
  const float* g2_wl = (const float*)d_in[13];
  const float* g2_bl = (const float*)d_in[14];
  const float* g2_wr = (const float*)d_in[15];
  const float* g2_br = (const float*)d_in[16];
  const float* g2_we = (const float*)d_in[17];
  const float* g2_att = (const float*)d_in[18];
  const float* g2_bias = (const float*)d_in[19];
  const float* p1_w = (const float*)d_in[20];
  const float* p1_b = (const float*)d_in[21];
  const float* ln_g = (const float*)d_in[22];
  const float* ln_b = (const float*)d_in[23];
  const float* p2_w = (const float*)d_in[24];
  const float* p2_b = (const float*)d_in[25];
  const float* hc_w = (const float*)d_in[26];
  const float* hc_b = (const float*)d_in[27];
  const float* hf_w = (const float*)d_in[28];
  const float* hf_b = (const float*)d_in[29];
  float* out = (float*)d_out;

  // ---- workspace layout ----
  ushort* xlb = (ushort*)d_ws;               // N*256 bf16
  ushort* xrb = xlb + (size_t)NN * 256;      // N*256 bf16
  ushort* hb = xrb + (size_t)NN * 256;       // N*256 bf16
  ushort* h0b = hb + (size_t)NN * 256;       // N*64 bf16
  ushort* w1l = h0b + (size_t)NN * 64;       // 256*64 bf16 (transposed)
  ushort* w1r = w1l + 256 * 64;
  ushort* w2l = w1r + 256 * 64;              // 256*256 bf16
  ushort* w2r = w2l + 256 * 256;
  int2* sedge = (int2*)(w2r + 256 * 256);    // EP (src, ea-bits)
  int* counts = (int*)(sedge + EP);          // NN
  int* offsets = counts + NN;                // NN
  int* cursor = offsets + NN;                // NN
  int* bsum = cursor + NN;                   // NBLK_SCAN
  float* sums = (float*)(bsum + NBLK_SCAN);  // B*256
  float* cnts = sums + (size_t)NB * 256;     // B
  float* esum = cnts + NB;                   // 1

  // ---- edge_attr mean ----
  hipMemsetAsync(esum, 0, sizeof(float), stream);
  reduce_sum_kernel<<<256, 256, 0, stream>>>(ea, esum);

  // ---- counting sort of edges by dst (graph static: reused by both layers) ----
  hipMemsetAsync(counts, 0, (size_t)NN * sizeof(int), stream);
  hist_kernel<<<1024, 256, 0, stream>>>(ei, counts);
  scanA_kernel<<<NBLK_SCAN, 256, 0, stream>>>(counts, bsum);
  scanB_kernel<<<1, 64, 0, stream>>>(bsum);
  scanC_kernel<<<NBLK_SCAN, 256, 0, stream>>>(counts, bsum, offsets, cursor);
  scatter_kernel<<<1024, 256, 0, stream>>>(ei, ea, esum, cursor, sedge);

  // ---- weight conversion (f32 [K][256] -> bf16 [256][K]) ----
  wconv_kernel<<<64, 256, 0, stream>>>(g1_wl, 6, w1l);
  wconv_kernel<<<64, 256, 0, stream>>>(g1_wr, 6, w1r);
  wconv_kernel<<<256, 256, 0, stream>>>(g2_wl, 8, w2l);
  wconv_kernel<<<256, 256, 0, stream>>>(g2_wr, 8, w2r);

  // ---- encoder ----
  encoder_kernel<<<(NN * 64 + 255) / 256, 256, 0, stream>>>(x, enc_w, enc_b, h0b);

  const int nGemmBlocks = (NN + 31) / 32;
  const int nGatBlocks = (NN + 3) / 4;

  // ================= GAT layer 1 (K=64) =================
  dual_linear_mfma<<<nGemmBlocks, 256, 0, stream>>>(h0b, 64, w1l, w1r, g1_bl, g1_br, xlb, xrb);
  gat_fused_kernel<<<nGatBlocks, 256, 0, stream>>>(offsets, counts, sedge, xlb, xrb,
                                                   g1_we, g1_att, g1_bias, hb);

  // ================= GAT layer 2 (K=256) =================
  dual_linear_mfma<<<nGemmBlocks, 256, 0, stream>>>(hb, 256, w2l, w2r, g2_bl, g2_br, xlb, xrb);
  gat_fused_kernel<<<nGatBlocks, 256, 0, stream>>>(offsets, counts, sedge, xlb, xrb,
                                                   g2_we, g2_att, g2_bias, hb);

  // ================= pool + head =================
  hipMemsetAsync(sums, 0, (size_t)NB * 256 * sizeof(float), stream);
  hipMemsetAsync(cnts, 0, (size_t)NB * sizeof(float), stream);
  pool_kernel<<<(NN + 127) / 128, 256, 0, stream>>>(hb, batch, sums, cnts);
  head_kernel<<<NB, 128, 0, stream>>>(sums, cnts, p1_w, p1_b, ln_g, ln_b, p2_w, p2_b,
                                      hc_w, hc_b, hf_w, hf_b, out);
}

// Round 7
// 370.420 us; speedup vs baseline: 1.9620x; 1.1305x over previous
//
#include <hip/hip_runtime.h>
#include <hip/hip_bf16.h>

#define NN 50000      // nodes
#define NE 500000     // edges (without self loops)
#define EP (NE + NN)  // edges with self loops
#define NB 50         // graphs
#define NEG 0.2f
#define NBLK_SCAN 196  // ceil(NN/256)
#define DEFER_THR 8.0f
#define GEMM_ROWS 128  // rows per dual_linear_pb block

typedef __attribute__((ext_vector_type(8))) short short8;
typedef __attribute__((ext_vector_type(4))) float f32x4;

__device__ __forceinline__ ushort f2bf(float f) {
  unsigned u = __float_as_uint(f);
  unsigned r = (u + 0x7FFFu + ((u >> 16) & 1u)) >> 16;
  return (ushort)r;
}
__device__ __forceinline__ float bf2f(ushort b) {
  return __uint_as_float(((unsigned)b) << 16);
}

// ---------- mean(edge_attr) : sum into esum[0] ----------
__global__ __launch_bounds__(256) void reduce_sum_kernel(const float* __restrict__ ea,
                                                         float* __restrict__ esum) {
  int t = blockIdx.x * 256 + threadIdx.x;
  float v = 0.f;
  for (int i = t; i < NE; i += gridDim.x * 256) v += ea[i];
  for (int off = 1; off < 64; off <<= 1) v += __shfl_xor(v, off, 64);
  if ((threadIdx.x & 63) == 0) atomicAdd(esum, v);
}

// ---------- weight convert+transpose: W[K][256] f32 -> Wt[256][K] bf16 ----------
__global__ __launch_bounds__(256) void wconv_kernel(const float* __restrict__ W,
                                                    int kshift,  // log2(K)
                                                    ushort* __restrict__ Wt) {
  int K = 1 << kshift;
  int t = blockIdx.x * 256 + threadIdx.x;
  if (t >= (K << 8)) return;
  int n = t >> kshift;
  int k = t & (K - 1);
  Wt[t] = f2bf(W[(size_t)k * 256 + n]);
}

// ---------- encoder: h0[n][j] = relu(x[n,:8] @ enc_w + enc_b), bf16 out ----------
__global__ __launch_bounds__(256) void encoder_kernel(const float* __restrict__ x,
                                                      const float* __restrict__ w,
                                                      const float* __restrict__ b,
                                                      ushort* __restrict__ h0) {
  int t = blockIdx.x * 256 + threadIdx.x;
  if (t >= NN * 64) return;
  int n = t >> 6, j = t & 63;
  float acc = b[j];
#pragma unroll
  for (int k = 0; k < 8; k++) acc += x[n * 8 + k] * w[k * 64 + j];
  h0[t] = f2bf(fmaxf(acc, 0.f));
}

// ---------- dual linear via MFMA, persistent-B form ----------
// Each wave owns 64 output cols; its B-slice (4 col-frags x K) lives in
// registers for the whole block; A rows stream through in 32-row subtiles.
// blockIdx.y selects Wl (0) or Wr (1). Grid.x covers rows in GEMM_ROWS tiles.
template <int K>
__global__ __launch_bounds__(256) void dual_linear_pb(const ushort* __restrict__ A,
                                                      const ushort* __restrict__ Wl,
                                                      const ushort* __restrict__ Wr,
                                                      const float* __restrict__ bl,
                                                      const float* __restrict__ br,
                                                      ushort* __restrict__ xl,
                                                      ushort* __restrict__ xr) {
  constexpr int NKS = K / 32;
  int wave = threadIdx.x >> 6, lane = threadIdx.x & 63;
  int lr = lane & 15;        // row-in-frag (A) / col-in-frag (B/D)
  int kb = (lane >> 4) * 8;  // k-base within 32-wide k-step
  const ushort* W = blockIdx.y ? Wr : Wl;
  const float* bias = blockIdx.y ? br : bl;
  ushort* O = blockIdx.y ? xr : xl;
  const int c0 = wave * 64;
  // persistent B fragments (loaded once; L2-resident weights)
  short8 b[4][NKS];
  const ushort* pb = W + (size_t)(c0 + lr) * K + kb;
#pragma unroll
  for (int fc = 0; fc < 4; fc++)
#pragma unroll
    for (int ks = 0; ks < NKS; ks++)
      b[fc][ks] = *(const short8*)(pb + (size_t)fc * 16 * K + ks * 32);

  int r0 = blockIdx.x * GEMM_ROWS;
  int rend = min(r0 + GEMM_ROWS, NN);
  for (int r = r0; r < rend; r += 32) {
    f32x4 acc[2][4];
#pragma unroll
    for (int fr = 0; fr < 2; fr++)
#pragma unroll
      for (int fc = 0; fc < 4; fc++) acc[fr][fc] = (f32x4){0.f, 0.f, 0.f, 0.f};
    int ra0 = min(r + lr, NN - 1);
    int ra1 = min(r + 16 + lr, NN - 1);
    const ushort* pa0 = A + (size_t)ra0 * K + kb;
    const ushort* pa1 = A + (size_t)ra1 * K + kb;
#pragma unroll
    for (int ks = 0; ks < NKS; ks++) {
      short8 a0 = *(const short8*)(pa0 + ks * 32);
      short8 a1 = *(const short8*)(pa1 + ks * 32);
#pragma unroll
      for (int fc = 0; fc < 4; fc++) {
        acc[0][fc] = __builtin_amdgcn_mfma_f32_16x16x32_bf16(a0, b[fc][ks], acc[0][fc], 0, 0, 0);
        acc[1][fc] = __builtin_amdgcn_mfma_f32_16x16x32_bf16(a1, b[fc][ks], acc[1][fc], 0, 0, 0);
      }
    }
#pragma unroll
    for (int fc = 0; fc < 4; fc++) {
      int c = c0 + fc * 16 + lr;
      float bv = bias[c];
#pragma unroll
      for (int fr = 0; fr < 2; fr++) {
#pragma unroll
        for (int j = 0; j < 4; j++) {
          int row = r + fr * 16 + (lane >> 4) * 4 + j;
          if (row < NN) O[(size_t)row * 256 + c] = f2bf(acc[fr][fc][j] + bv);
        }
      }
    }
  }
}

// ================= counting sort of edges by dst =================
__global__ __launch_bounds__(256) void hist_kernel(const int* __restrict__ ei,
                                                   int* __restrict__ counts) {
  int t = blockIdx.x * 256 + threadIdx.x;
  for (int e = t; e < EP; e += gridDim.x * 256) {
    int dst = (e < NE) ? ei[NE + e] : e - NE;
    atomicAdd(&counts[dst], 1);
  }
}

__global__ __launch_bounds__(256) void scanA_kernel(const int* __restrict__ counts,
                                                    int* __restrict__ bsum) {
  int i = blockIdx.x * 256 + threadIdx.x;
  int v = (i < NN) ? counts[i] : 0;
  for (int off = 1; off < 64; off <<= 1) v += __shfl_xor(v, off, 64);
  __shared__ int sw[4];
  if ((threadIdx.x & 63) == 0) sw[threadIdx.x >> 6] = v;
  __syncthreads();
  if (threadIdx.x == 0) bsum[blockIdx.x] = sw[0] + sw[1] + sw[2] + sw[3];
}

__global__ void scanB_kernel(int* __restrict__ bsum) {
  if (threadIdx.x == 0 && blockIdx.x == 0) {
    int run = 0;
    for (int b = 0; b < NBLK_SCAN; b++) {
      int v = bsum[b];
      bsum[b] = run;
      run += v;
    }
  }
}

__global__ __launch_bounds__(256) void scanC_kernel(const int* __restrict__ counts,
                                                    const int* __restrict__ bpre,
                                                    int* __restrict__ offsets,
                                                    int* __restrict__ cursor) {
  __shared__ int s[256];
  int i = blockIdx.x * 256 + threadIdx.x;
  int v = (i < NN) ? counts[i] : 0;
  s[threadIdx.x] = v;
  __syncthreads();
  for (int off = 1; off < 256; off <<= 1) {
    int add = (threadIdx.x >= off) ? s[threadIdx.x - off] : 0;
    __syncthreads();
    s[threadIdx.x] += add;
    __syncthreads();
  }
  if (i < NN) {
    int excl = s[threadIdx.x] - v + bpre[blockIdx.x];
    offsets[i] = excl;
    cursor[i] = excl;
  }
}

// scatter packed (src, edge_attr) per edge, bucketed by dst
__global__ __launch_bounds__(256) void scatter_kernel(const int* __restrict__ ei,
                                                      const float* __restrict__ ea,
                                                      const float* __restrict__ esum,
                                                      int* __restrict__ cursor,
                                                      int2* __restrict__ sedge) {
  int t = blockIdx.x * 256 + threadIdx.x;
  float mean = esum[0] * (1.0f / NE);
  for (int e = t; e < EP; e += gridDim.x * 256) {
    int src, dst;
    float v;
    if (e < NE) {
      src = ei[e];
      dst = ei[NE + e];
      v = ea[e];
    } else {
      src = dst = e - NE;
      v = mean;
    }
    int pos = atomicAdd(&cursor[dst], 1);
    sedge[pos] = make_int2(src, __float_as_int(v));
  }
}

// ================= fused GATv2 edge phase =================
// One wave per dst. Lane l owns elems l*4..l*4+3 (head l>>4).
// leaky_relu(v) = 0.6v + 0.4|v| folded into att-dot; defer-max softmax (THR=8)
// -> commutative fast path, 2 edges/iter with 2-ahead prefetch; packed int2 edges.
__global__ __launch_bounds__(256) void gat_fused_kernel(const int* __restrict__ offsets,
                                                        const int* __restrict__ counts,
                                                        const int2* __restrict__ sedge,
                                                        const ushort* __restrict__ xl,
                                                        const ushort* __restrict__ xr,
                                                        const float* __restrict__ we,
                                                        const float* __restrict__ att,
                                                        const float* __restrict__ bias,
                                                        ushort* __restrict__ hb) {
  int w = threadIdx.x >> 6, lane = threadIdx.x & 63;
  int d = blockIdx.x * 4 + w;
  if (d >= NN) return;
  int off = offsets[d], cnt = counts[d];
  const int c4 = lane * 4;
  ushort4 xru = *(const ushort4*)(xr + (size_t)d * 256 + c4);
  const float4 xr4 = {bf2f(xru.x), bf2f(xru.y), bf2f(xru.z), bf2f(xru.w)};
  const float4 we4 = *(const float4*)(we + c4);
  const float4 at4 = *(const float4*)(att + c4);
  const float4 a06 = {0.6f * at4.x, 0.6f * at4.y, 0.6f * at4.z, 0.6f * at4.w};
  const float4 a04 = {0.4f * at4.x, 0.4f * at4.y, 0.4f * at4.z, 0.4f * at4.w};
  float4 acc = {0.f, 0.f, 0.f, 0.f};
  float den = 0.f, m = -1e30f;
  const int2* pe = sedge + off;
  // pipeline registers (pair i, pair i+2 prefetched)
  ushort4 xu0 = {0, 0, 0, 0}, xu1 = {0, 0, 0, 0};
  float ea0 = 0.f, ea1 = 0.f;
  {
    int2 e0 = pe[0];
    xu0 = *(const ushort4*)(xl + (size_t)e0.x * 256 + c4);
    ea0 = __int_as_float(e0.y);
    if (1 < cnt) {
      int2 e1 = pe[1];
      xu1 = *(const ushort4*)(xl + (size_t)e1.x * 256 + c4);
      ea1 = __int_as_float(e1.y);
    }
  }
  for (int i = 0; i < cnt; i += 2) {
    ushort4 cx0 = xu0, cx1 = xu1;
    float ce0 = ea0, ce1 = ea1;
    bool e1v = (i + 1) < cnt;
    if (i + 2 < cnt) {  // prefetch next pair
      int2 e0 = pe[i + 2];
      xu0 = *(const ushort4*)(xl + (size_t)e0.x * 256 + c4);
      ea0 = __int_as_float(e0.y);
      if (i + 3 < cnt) {
        int2 e1 = pe[i + 3];
        xu1 = *(const ushort4*)(xl + (size_t)e1.x * 256 + c4);
        ea1 = __int_as_float(e1.y);
      }
    }
    float4 xf0 = {bf2f(cx0.x), bf2f(cx0.y), bf2f(cx0.z), bf2f(cx0.w)};
    float4 xf1 = {bf2f(cx1.x), bf2f(cx1.y), bf2f(cx1.z), bf2f(cx1.w)};
    float v00 = xf0.x + fmaf(ce0, we4.x, xr4.x);
    float v01 = xf0.y + fmaf(ce0, we4.y, xr4.y);
    float v02 = xf0.z + fmaf(ce0, we4.z, xr4.z);
    float v03 = xf0.w + fmaf(ce0, we4.w, xr4.w);
    float v10 = xf1.x + fmaf(ce1, we4.x, xr4.x);
    float v11 = xf1.y + fmaf(ce1, we4.y, xr4.y);
    float v12 = xf1.z + fmaf(ce1, we4.z, xr4.z);
    float v13 = xf1.w + fmaf(ce1, we4.w, xr4.w);
    float p0 = fmaf(a06.x, v00, a04.x * fabsf(v00));
    p0 = fmaf(a06.y, v01, fmaf(a04.y, fabsf(v01), p0));
    p0 = fmaf(a06.z, v02, fmaf(a04.z, fabsf(v02), p0));
    p0 = fmaf(a06.w, v03, fmaf(a04.w, fabsf(v03), p0));
    float p1 = fmaf(a06.x, v10, a04.x * fabsf(v10));
    p1 = fmaf(a06.y, v11, fmaf(a04.y, fabsf(v11), p1));
    p1 = fmaf(a06.z, v12, fmaf(a04.z, fabsf(v12), p1));
    p1 = fmaf(a06.w, v13, fmaf(a04.w, fabsf(v13), p1));
    p0 += __shfl_xor(p0, 1, 64);
    p0 += __shfl_xor(p0, 2, 64);
    p0 += __shfl_xor(p0, 4, 64);
    p0 += __shfl_xor(p0, 8, 64);
    p1 += __shfl_xor(p1, 1, 64);
    p1 += __shfl_xor(p1, 2, 64);
    p1 += __shfl_xor(p1, 4, 64);
    p1 += __shfl_xor(p1, 8, 64);
    float thrm = m + DEFER_THR;
    if (__all((p0 <= thrm) && (!e1v || p1 <= thrm))) {
      // fast path: m unchanged, commutative accumulation
      float ex0 = __expf(p0 - m);
      float ex1 = e1v ? __expf(p1 - m) : 0.f;
      den += ex0 + ex1;
      acc.x = fmaf(xf0.x, ex0, fmaf(xf1.x, ex1, acc.x));
      acc.y = fmaf(xf0.y, ex0, fmaf(xf1.y, ex1, acc.y));
      acc.z = fmaf(xf0.z, ex0, fmaf(xf1.z, ex1, acc.z));
      acc.w = fmaf(xf0.w, ex0, fmaf(xf1.w, ex1, acc.w));
    } else {
      // slow path: full online update per edge
      {
        float mn = fmaxf(m, p0);
        float sc = __expf(m - mn);
        float ex = __expf(p0 - mn);
        den = fmaf(den, sc, ex);
        acc.x = fmaf(acc.x, sc, xf0.x * ex);
        acc.y = fmaf(acc.y, sc, xf0.y * ex);
        acc.z = fmaf(acc.z, sc, xf0.z * ex);
        acc.w = fmaf(acc.w, sc, xf0.w * ex);
        m = mn;
      }
      if (e1v) {
        float mn = fmaxf(m, p1);
        float sc = __expf(m - mn);
        float ex = __expf(p1 - mn);
        den = fmaf(den, sc, ex);
        acc.x = fmaf(acc.x, sc, xf1.x * ex);
        acc.y = fmaf(acc.y, sc, xf1.y * ex);
        acc.z = fmaf(acc.z, sc, xf1.z * ex);
        acc.w = fmaf(acc.w, sc, xf1.w * ex);
        m = mn;
      }
    }
  }
  const float4 b4 = *(const float4*)(bias + c4);
  float inv = 1.f / den;  // every node has a self-loop -> den > 0
  ushort4 o;
  o.x = f2bf(fmaxf(fmaf(acc.x, inv, b4.x), 0.f));
  o.y = f2bf(fmaxf(fmaf(acc.y, inv, b4.y), 0.f));
  o.z = f2bf(fmaxf(fmaf(acc.z, inv, b4.z), 0.f));
  o.w = f2bf(fmaxf(fmaf(acc.w, inv, b4.w), 0.f));
  *(ushort4*)(hb + (size_t)d * 256 + c4) = o;
}

// ---------- global mean pool (batch is sorted; run-length flush) ----------
__global__ __launch_bounds__(256) void pool_kernel(const ushort* __restrict__ h,
                                                   const int* __restrict__ batch,
                                                   float* __restrict__ sums,
                                                   float* __restrict__ cnts) {
  __shared__ int sb[128];
  int n0 = blockIdx.x * 128;
  int j = threadIdx.x;
  int count = min(128, NN - n0);
  if (count <= 0) return;
  for (int t = threadIdx.x; t < count; t += 256) sb[t] = batch[n0 + t];
  __syncthreads();
  float acc = 0.f;
  int run = 0;
  int cur = sb[0];
  for (int i = 0; i < count; ++i) {
    int b = sb[i];
    if (b != cur) {
      atomicAdd(&sums[(size_t)cur * 256 + j], acc);
      if (j == 0) atomicAdd(&cnts[cur], (float)run);
      acc = 0.f;
      run = 0;
      cur = b;
    }
    acc += bf2f(h[(size_t)(n0 + i) * 256 + j]);
    run++;
  }
  atomicAdd(&sums[(size_t)cur * 256 + j], acc);
  if (j == 0) atomicAdd(&cnts[cur], (float)run);
}

// ---------- post-MLP head: one block per graph ----------
__global__ __launch_bounds__(128) void head_kernel(const float* __restrict__ sums,
                                                   const float* __restrict__ cnts,
                                                   const float* __restrict__ p1_w,
                                                   const float* __restrict__ p1_b,
                                                   const float* __restrict__ ln_g,
                                                   const float* __restrict__ ln_b,
                                                   const float* __restrict__ p2_w,
                                                   const float* __restrict__ p2_b,
                                                   const float* __restrict__ hc_w,
                                                   const float* __restrict__ hc_b,
                                                   const float* __restrict__ hf_w,
                                                   const float* __restrict__ hf_b,
                                                   float* __restrict__ out) {
  int g = blockIdx.x;
  int j = threadIdx.x;  // 0..127
  __shared__ float sp[256], st[128], sz[64];
  float cnt = fmaxf(cnts[g], 1.0f);
  for (int t = j; t < 256; t += 128) sp[t] = sums[(size_t)g * 256 + t] / cnt;
  __syncthreads();
  float acc = p1_b[j];
  for (int k = 0; k < 256; k++) acc += sp[k] * p1_w[(size_t)k * 128 + j];
  st[j] = acc;
  __syncthreads();
  float mu = 0.f;
  for (int k = 0; k < 128; k++) mu += st[k];
  mu *= (1.f / 128.f);
  float var = 0.f;
  for (int k = 0; k < 128; k++) {
    float d = st[k] - mu;
    var += d * d;
  }
  var *= (1.f / 128.f);
  float tj = (acc - mu) * rsqrtf(var + 1e-5f) * ln_g[j] + ln_b[j];
  tj = fmaxf(tj, 0.f);
  __syncthreads();
  st[j] = tj;
  __syncthreads();
  if (j < 64) {
    float z = p2_b[j];
    for (int k = 0; k < 128; k++) z += st[k] * p2_w[(size_t)k * 64 + j];
    z = fmaxf(z, 0.f);
    sz[j] = z;
    out[500 + (size_t)g * 64 + j] = z;  // output 2: z [B,64]
  }
  __syncthreads();
  if (j == 0) {
    float c = hc_b[0];
    for (int k = 0; k < 64; k++) c += sz[k] * hc_w[k];
    out[g] = c;  // output 0: cooling [B]
  }
  if (j >= 1 && j < 10) {
    int f = j - 1;
    float v = hf_b[f];
    for (int k = 0; k < 64; k++) v += sz[k] * hf_w[(size_t)k * 9 + f];
    out[50 + (size_t)g * 9 + f] = v;  // output 1: fatigue [B,9]
  }
}

extern "C" void kernel_launch(void* const* d_in, const int* in_sizes, int n_in,
                              void* d_out, int out_size, void* d_ws, size_t ws_size,
                              hipStream_t stream) {
  const float* x = (const float*)d_in[0];
  const int* ei = (const int*)d_in[1];
  const float* ea = (const float*)d_in[2];
  const int* batch = (const int*)d_in[3];
  const float* enc_w = (const float*)d_in[4];
  const float* enc_b = (const float*)d_in[5];
  const float* g1_wl = (const float*)d_in[6];
  const float* g1_bl = (const float*)d_in[7];
  const float* g1_wr = (const float*)d_in[8];
  const float* g1_br = (const float*)d_in[9];
  const float* g1_we = (const float*)d_in[10];
  const float* g1_att = (const float*)d_in[11];
  const float* g1_bias = (const float*)d_in[12];
  const float* g2_wl = (const float*)d_in[13];
  const float* g2_bl = (const float*)d_in[14];
  const float* g2_wr = (const float*)d_in[15];
  const float* g2_br = (const float*)d_in[16];
  const float* g2_we = (const float*)d_in[17];
  const float* g2_att = (const float*)d_in[18];
  const float* g2_bias = (const float*)d_in[19];
  const float* p1_w = (const float*)d_in[20];
  const float* p1_b = (const float*)d_in[21];
  const float* ln_g = (const float*)d_in[22];
  const float* ln_b = (const float*)d_in[23];
  const float* p2_w = (const float*)d_in[24];
  const float* p2_b = (const float*)d_in[25];
  const float* hc_w = (const float*)d_in[26];
  const float* hc_b = (const float*)d_in[27];
  const float* hf_w = (const float*)d_in[28];
  const float* hf_b = (const float*)d_in[29];
  float* out = (float*)d_out;

  // ---- workspace layout ----
  ushort* xlb = (ushort*)d_ws;               // N*256 bf16
  ushort* xrb = xlb + (size_t)NN * 256;      // N*256 bf16
  ushort* hb = xrb + (size_t)NN * 256;       // N*256 bf16
  ushort* h0b = hb + (size_t)NN * 256;       // N*64 bf16
  ushort* w1l = h0b + (size_t)NN * 64;       // 256*64 bf16 (transposed)
  ushort* w1r = w1l + 256 * 64;
  ushort* w2l = w1r + 256 * 64;              // 256*256 bf16
  ushort* w2r = w2l + 256 * 256;
  int2* sedge = (int2*)(w2r + 256 * 256);    // EP (src, ea-bits)
  int* counts = (int*)(sedge + EP);          // NN
  int* offsets = counts + NN;                // NN
  int* cursor = offsets + NN;                // NN
  int* bsum = cursor + NN;                   // NBLK_SCAN
  float* sums = (float*)(bsum + NBLK_SCAN);  // B*256
  float* cnts = sums + (size_t)NB * 256;     // B
  float* esum = cnts + NB;                   // 1

  // ---- edge_attr mean ----
  hipMemsetAsync(esum, 0, sizeof(float), stream);
  reduce_sum_kernel<<<256, 256, 0, stream>>>(ea, esum);

  // ---- counting sort of edges by dst (graph static: reused by both layers) ----
  hipMemsetAsync(counts, 0, (size_t)NN * sizeof(int), stream);
  hist_kernel<<<1024, 256, 0, stream>>>(ei, counts);
  scanA_kernel<<<NBLK_SCAN, 256, 0, stream>>>(counts, bsum);
  scanB_kernel<<<1, 64, 0, stream>>>(bsum);
  scanC_kernel<<<NBLK_SCAN, 256, 0, stream>>>(counts, bsum, offsets, cursor);
  scatter_kernel<<<1024, 256, 0, stream>>>(ei, ea, esum, cursor, sedge);

  // ---- weight conversion (f32 [K][256] -> bf16 [256][K]) ----
  wconv_kernel<<<64, 256, 0, stream>>>(g1_wl, 6, w1l);
  wconv_kernel<<<64, 256, 0, stream>>>(g1_wr, 6, w1r);
  wconv_kernel<<<256, 256, 0, stream>>>(g2_wl, 8, w2l);
  wconv_kernel<<<256, 256, 0, stream>>>(g2_wr, 8, w2r);

  // ---- encoder ----
  encoder_kernel<<<(NN * 64 + 255) / 256, 256, 0, stream>>>(x, enc_w, enc_b, h0b);

  const dim3 gemmGrid((NN + GEMM_ROWS - 1) / GEMM_ROWS, 2);
  const int nGatBlocks = (NN + 3) / 4;

  // ================= GAT layer 1 (K=64) =================
  dual_linear_pb<64><<<gemmGrid, 256, 0, stream>>>(h0b, w1l, w1r, g1_bl, g1_br, xlb, xrb);
  gat_fused_kernel<<<nGatBlocks, 256, 0, stream>>>(offsets, counts, sedge, xlb, xrb,
                                                   g1_we, g1_att, g1_bias, hb);

  // ================= GAT layer 2 (K=256) =================
  dual_linear_pb<256><<<gemmGrid, 256, 0, stream>>>(hb, w2l, w2r, g2_bl, g2_br, xlb, xrb);
  gat_fused_kernel<<<nGatBlocks, 256, 0, stream>>>(offsets, counts, sedge, xlb, xrb,
                                                   g2_we, g2_att, g2_bias, hb);

  // ================= pool + head =================
  hipMemsetAsync(sums, 0, (size_t)NB * 256 * sizeof(float), stream);
  hipMemsetAsync(cnts, 0, (size_t)NB * sizeof(float), stream);
  pool_kernel<<<(NN + 127) / 128, 256, 0, stream>>>(hb, batch, sums, cnts);
  head_kernel<<<NB, 128, 0, stream>>>(sums, cnts, p1_w, p1_b, ln_g, ln_b, p2_w, p2_b,
                                      hc_w, hc_b, hf_w, hf_b, out);
}

// Round 8
// 368.138 us; speedup vs baseline: 1.9742x; 1.0062x over previous
//
#include <hip/hip_runtime.h>
#include <hip/hip_bf16.h>

#define NN 50000      // nodes
#define NE 500000     // edges (without self loops)
#define EP (NE + NN)  // edges with self loops
#define NB 50         // graphs
#define NEG 0.2f
#define NBLK_SCAN 196  // ceil(NN/256)
#define GEMM_ROWS 128  // rows per dual_linear_pb block

typedef __attribute__((ext_vector_type(8))) short short8;
typedef __attribute__((ext_vector_type(4))) float f32x4;

__device__ __forceinline__ ushort f2bf(float f) {
  unsigned u = __float_as_uint(f);
  unsigned r = (u + 0x7FFFu + ((u >> 16) & 1u)) >> 16;
  return (ushort)r;
}
__device__ __forceinline__ float bf2f(ushort b) {
  return __uint_as_float(((unsigned)b) << 16);
}

// hardware exp2 (v_exp_f32 is 2^x); s_nop covers the trans->VALU wait state
__device__ __forceinline__ float exp2s(float x) {
  float r;
  asm("v_exp_f32 %0, %1\ns_nop 0" : "=v"(r) : "v"(x));
  return r;
}

// all-lanes sum within each 16-lane row (head group), pure-VALU DPP:
// quad xor1, quad xor2, then row_ror:4 + row_ror:8 covers all 4 quads.
__device__ __forceinline__ float row_reduce16(float x) {
  x += __int_as_float(__builtin_amdgcn_mov_dpp(__float_as_int(x), 0xB1, 0xF, 0xF, true));
  x += __int_as_float(__builtin_amdgcn_mov_dpp(__float_as_int(x), 0x4E, 0xF, 0xF, true));
  x += __int_as_float(__builtin_amdgcn_mov_dpp(__float_as_int(x), 0x124, 0xF, 0xF, true));
  x += __int_as_float(__builtin_amdgcn_mov_dpp(__float_as_int(x), 0x128, 0xF, 0xF, true));
  return x;
}

// ---------- fused: mean(edge_attr) partial-sums + dst histogram ----------
__global__ __launch_bounds__(256) void prep_kernel(const float* __restrict__ ea,
                                                   float* __restrict__ esum,
                                                   const int* __restrict__ ei,
                                                   int* __restrict__ counts) {
  int t = blockIdx.x * 256 + threadIdx.x;
  float v = 0.f;
  for (int i = t; i < NE; i += 262144) v += ea[i];
  for (int off = 1; off < 64; off <<= 1) v += __shfl_xor(v, off, 64);
  if ((threadIdx.x & 63) == 0) atomicAdd(esum, v);
  for (int e = t; e < EP; e += 262144) {
    int dst = (e < NE) ? ei[NE + e] : e - NE;
    atomicAdd(&counts[dst], 1);
  }
}

// ---------- all 4 weight converts (f32 [K][256] -> bf16 [256][K]) in one ----------
__global__ __launch_bounds__(256) void wconv_all(const float* __restrict__ g1_wl,
                                                 const float* __restrict__ g1_wr,
                                                 const float* __restrict__ g2_wl,
                                                 const float* __restrict__ g2_wr,
                                                 ushort* __restrict__ w1l,
                                                 ushort* __restrict__ w1r,
                                                 ushort* __restrict__ w2l,
                                                 ushort* __restrict__ w2r) {
  int b = blockIdx.x, t = threadIdx.x;
  if (b < 128) {  // layer-1 weights, K=64
    int sec = b >> 6;
    const float* W = sec ? g1_wr : g1_wl;
    ushort* Wt = sec ? w1r : w1l;
    int i = (b & 63) * 256 + t;
    int n = i >> 6, k = i & 63;
    Wt[i] = f2bf(W[(size_t)k * 256 + n]);
  } else {  // layer-2 weights, K=256
    int bb = b - 128;
    int sec = bb >> 8;
    const float* W = sec ? g2_wr : g2_wl;
    ushort* Wt = sec ? w2r : w2l;
    int i = (bb & 255) * 256 + t;
    int n = i >> 8, k = i & 255;
    Wt[i] = f2bf(W[(size_t)k * 256 + n]);
  }
}

// ---------- encoder: h0[n][j] = relu(x[n,:8] @ enc_w + enc_b), bf16 out ----------
__global__ __launch_bounds__(256) void encoder_kernel(const float* __restrict__ x,
                                                      const float* __restrict__ w,
                                                      const float* __restrict__ b,
                                                      ushort* __restrict__ h0) {
  int t = blockIdx.x * 256 + threadIdx.x;
  if (t >= NN * 64) return;
  int n = t >> 6, j = t & 63;
  float acc = b[j];
#pragma unroll
  for (int k = 0; k < 8; k++) acc += x[n * 8 + k] * w[k * 64 + j];
  h0[t] = f2bf(fmaxf(acc, 0.f));
}

// ---------- dual linear via MFMA, persistent-B form ----------
template <int K>
__global__ __launch_bounds__(256) void dual_linear_pb(const ushort* __restrict__ A,
                                                      const ushort* __restrict__ Wl,
                                                      const ushort* __restrict__ Wr,
                                                      const float* __restrict__ bl,
                                                      const float* __restrict__ br,
                                                      ushort* __restrict__ xl,
                                                      ushort* __restrict__ xr) {
  constexpr int NKS = K / 32;
  int wave = threadIdx.x >> 6, lane = threadIdx.x & 63;
  int lr = lane & 15;        // row-in-frag (A) / col-in-frag (B/D)
  int kb = (lane >> 4) * 8;  // k-base within 32-wide k-step
  const ushort* W = blockIdx.y ? Wr : Wl;
  const float* bias = blockIdx.y ? br : bl;
  ushort* O = blockIdx.y ? xr : xl;
  const int c0 = wave * 64;
  short8 b[4][NKS];
  const ushort* pb = W + (size_t)(c0 + lr) * K + kb;
#pragma unroll
  for (int fc = 0; fc < 4; fc++)
#pragma unroll
    for (int ks = 0; ks < NKS; ks++)
      b[fc][ks] = *(const short8*)(pb + (size_t)fc * 16 * K + ks * 32);

  int r0 = blockIdx.x * GEMM_ROWS;
  int rend = min(r0 + GEMM_ROWS, NN);
  for (int r = r0; r < rend; r += 32) {
    f32x4 acc[2][4];
#pragma unroll
    for (int fr = 0; fr < 2; fr++)
#pragma unroll
      for (int fc = 0; fc < 4; fc++) acc[fr][fc] = (f32x4){0.f, 0.f, 0.f, 0.f};
    int ra0 = min(r + lr, NN - 1);
    int ra1 = min(r + 16 + lr, NN - 1);
    const ushort* pa0 = A + (size_t)ra0 * K + kb;
    const ushort* pa1 = A + (size_t)ra1 * K + kb;
#pragma unroll
    for (int ks = 0; ks < NKS; ks++) {
      short8 a0 = *(const short8*)(pa0 + ks * 32);
      short8 a1 = *(const short8*)(pa1 + ks * 32);
#pragma unroll
      for (int fc = 0; fc < 4; fc++) {
        acc[0][fc] = __builtin_amdgcn_mfma_f32_16x16x32_bf16(a0, b[fc][ks], acc[0][fc], 0, 0, 0);
        acc[1][fc] = __builtin_amdgcn_mfma_f32_16x16x32_bf16(a1, b[fc][ks], acc[1][fc], 0, 0, 0);
      }
    }
#pragma unroll
    for (int fc = 0; fc < 4; fc++) {
      int c = c0 + fc * 16 + lr;
      float bv = bias[c];
#pragma unroll
      for (int fr = 0; fr < 2; fr++) {
#pragma unroll
        for (int j = 0; j < 4; j++) {
          int row = r + fr * 16 + (lane >> 4) * 4 + j;
          if (row < NN) O[(size_t)row * 256 + c] = f2bf(acc[fr][fc][j] + bv);
        }
      }
    }
  }
}

// ================= counting-sort scans =================
__global__ __launch_bounds__(256) void scanA_kernel(const int* __restrict__ counts,
                                                    int* __restrict__ bsum) {
  int i = blockIdx.x * 256 + threadIdx.x;
  int v = (i < NN) ? counts[i] : 0;
  for (int off = 1; off < 64; off <<= 1) v += __shfl_xor(v, off, 64);
  __shared__ int sw[4];
  if ((threadIdx.x & 63) == 0) sw[threadIdx.x >> 6] = v;
  __syncthreads();
  if (threadIdx.x == 0) bsum[blockIdx.x] = sw[0] + sw[1] + sw[2] + sw[3];
}

// parallel exclusive scan of the NBLK_SCAN block sums (single 256-thr block)
__global__ __launch_bounds__(256) void scanB_kernel(int* __restrict__ bsum) {
  __shared__ int s[256];
  int i = threadIdx.x;
  int v = (i < NBLK_SCAN) ? bsum[i] : 0;
  s[i] = v;
  __syncthreads();
  for (int off = 1; off < 256; off <<= 1) {
    int add = (i >= off) ? s[i - off] : 0;
    __syncthreads();
    s[i] += add;
    __syncthreads();
  }
  if (i < NBLK_SCAN) bsum[i] = s[i] - v;  // exclusive prefix
}

__global__ __launch_bounds__(256) void scanC_kernel(const int* __restrict__ counts,
                                                    const int* __restrict__ bpre,
                                                    int* __restrict__ offsets,
                                                    int* __restrict__ cursor) {
  __shared__ int s[256];
  int i = blockIdx.x * 256 + threadIdx.x;
  int v = (i < NN) ? counts[i] : 0;
  s[threadIdx.x] = v;
  __syncthreads();
  for (int off = 1; off < 256; off <<= 1) {
    int add = (threadIdx.x >= off) ? s[threadIdx.x - off] : 0;
    __syncthreads();
    s[threadIdx.x] += add;
    __syncthreads();
  }
  if (i < NN) {
    int excl = s[threadIdx.x] - v + bpre[blockIdx.x];
    offsets[i] = excl;
    cursor[i] = excl;
  }
}

// scatter packed (src, edge_attr) per edge, bucketed by dst; writes 4-entry tail pad
__global__ __launch_bounds__(256) void scatter_kernel(const int* __restrict__ ei,
                                                      const float* __restrict__ ea,
                                                      const float* __restrict__ esum,
                                                      int* __restrict__ cursor,
                                                      int2* __restrict__ sedge) {
  int t = blockIdx.x * 256 + threadIdx.x;
  if (t < 4) sedge[EP + t] = make_int2(0, 0);  // prefetch-safety pad
  float mean = esum[0] * (1.0f / NE);
  for (int e = t; e < EP; e += gridDim.x * 256) {
    int src, dst;
    float v;
    if (e < NE) {
      src = ei[e];
      dst = ei[NE + e];
      v = ea[e];
    } else {
      src = dst = e - NE;
      v = mean;
    }
    int pos = atomicAdd(&cursor[dst], 1);
    sedge[pos] = make_int2(src, __float_as_int(v));
  }
}

// ================= fused GATv2 edge phase =================
// One wave per dst. Lane l owns elems l*4..l*4+3 (head group = 16-lane DPP row).
// att pre-scaled by log2(e): softmax done in exp2 domain (exact same ratios).
// No max-tracking (logits bounded; clamp@120 for safety). Branchless 2-wide
// pipeline: sedge is padded so pe[i+2],pe[i+3] are always readable; odd tail
// handled by a single ex1=0 select.
__global__ __launch_bounds__(256) void gat_fused_kernel(const int* __restrict__ offsets,
                                                        const int* __restrict__ counts,
                                                        const int2* __restrict__ sedge,
                                                        const ushort* __restrict__ xl,
                                                        const ushort* __restrict__ xr,
                                                        const float* __restrict__ we,
                                                        const float* __restrict__ att,
                                                        const float* __restrict__ bias,
                                                        ushort* __restrict__ hb) {
  int w = threadIdx.x >> 6, lane = threadIdx.x & 63;
  int d = blockIdx.x * 4 + w;
  if (d >= NN) return;
  int off = offsets[d], cnt = counts[d];
  const int c4 = lane * 4;
  ushort4 xru = *(const ushort4*)(xr + (size_t)d * 256 + c4);
  const float4 xr4 = {bf2f(xru.x), bf2f(xru.y), bf2f(xru.z), bf2f(xru.w)};
  const float4 we4 = *(const float4*)(we + c4);
  const float4 at4 = *(const float4*)(att + c4);
  const float L2E = 1.44269504f;
  const float4 a06 = {0.6f * L2E * at4.x, 0.6f * L2E * at4.y, 0.6f * L2E * at4.z,
                      0.6f * L2E * at4.w};
  const float4 a04 = {0.4f * L2E * at4.x, 0.4f * L2E * at4.y, 0.4f * L2E * at4.z,
                      0.4f * L2E * at4.w};
  float4 acc = {0.f, 0.f, 0.f, 0.f};
  float den = 0.f;
  const int2* pe = sedge + off;
  int2 e0 = pe[0];
  int2 e1 = pe[1];
  ushort4 xu0 = *(const ushort4*)(xl + (size_t)e0.x * 256 + c4);
  ushort4 xu1 = *(const ushort4*)(xl + (size_t)e1.x * 256 + c4);
  for (int i = 0; i < cnt; i += 2) {
    float ce0 = __int_as_float(e0.y), ce1 = __int_as_float(e1.y);
    ushort4 cx0 = xu0, cx1 = xu1;
    e0 = pe[i + 2];  // always in-bounds (global pad)
    e1 = pe[i + 3];
    xu0 = *(const ushort4*)(xl + (size_t)e0.x * 256 + c4);
    xu1 = *(const ushort4*)(xl + (size_t)e1.x * 256 + c4);
    float4 xf0 = {bf2f(cx0.x), bf2f(cx0.y), bf2f(cx0.z), bf2f(cx0.w)};
    float4 xf1 = {bf2f(cx1.x), bf2f(cx1.y), bf2f(cx1.z), bf2f(cx1.w)};
    float v00 = xf0.x + fmaf(ce0, we4.x, xr4.x);
    float v01 = xf0.y + fmaf(ce0, we4.y, xr4.y);
    float v02 = xf0.z + fmaf(ce0, we4.z, xr4.z);
    float v03 = xf0.w + fmaf(ce0, we4.w, xr4.w);
    float v10 = xf1.x + fmaf(ce1, we4.x, xr4.x);
    float v11 = xf1.y + fmaf(ce1, we4.y, xr4.y);
    float v12 = xf1.z + fmaf(ce1, we4.z, xr4.z);
    float v13 = xf1.w + fmaf(ce1, we4.w, xr4.w);
    float p0 = fmaf(a06.x, v00, a04.x * fabsf(v00));
    p0 = fmaf(a06.y, v01, fmaf(a04.y, fabsf(v01), p0));
    p0 = fmaf(a06.z, v02, fmaf(a04.z, fabsf(v02), p0));
    p0 = fmaf(a06.w, v03, fmaf(a04.w, fabsf(v03), p0));
    float p1 = fmaf(a06.x, v10, a04.x * fabsf(v10));
    p1 = fmaf(a06.y, v11, fmaf(a04.y, fabsf(v11), p1));
    p1 = fmaf(a06.z, v12, fmaf(a04.z, fabsf(v12), p1));
    p1 = fmaf(a06.w, v13, fmaf(a04.w, fabsf(v13), p1));
    p0 = row_reduce16(p0);
    p1 = row_reduce16(p1);
    float ex0 = exp2s(fminf(p0, 120.f));
    float ex1 = exp2s(fminf(p1, 120.f));
    ex1 = (i + 1 < cnt) ? ex1 : 0.f;  // mask odd tail (wave-uniform select)
    den += ex0 + ex1;
    acc.x = fmaf(xf0.x, ex0, fmaf(xf1.x, ex1, acc.x));
    acc.y = fmaf(xf0.y, ex0, fmaf(xf1.y, ex1, acc.y));
    acc.z = fmaf(xf0.z, ex0, fmaf(xf1.z, ex1, acc.z));
    acc.w = fmaf(xf0.w, ex0, fmaf(xf1.w, ex1, acc.w));
  }
  const float4 b4 = *(const float4*)(bias + c4);
  float inv = 1.f / den;  // every node has a self-loop -> den > 0
  ushort4 o;
  o.x = f2bf(fmaxf(fmaf(acc.x, inv, b4.x), 0.f));
  o.y = f2bf(fmaxf(fmaf(acc.y, inv, b4.y), 0.f));
  o.z = f2bf(fmaxf(fmaf(acc.z, inv, b4.z), 0.f));
  o.w = f2bf(fmaxf(fmaf(acc.w, inv, b4.w), 0.f));
  *(ushort4*)(hb + (size_t)d * 256 + c4) = o;
}

// ---------- global mean pool (batch is sorted; run-length flush) ----------
__global__ __launch_bounds__(256) void pool_kernel(const ushort* __restrict__ h,
                                                   const int* __restrict__ batch,
                                                   float* __restrict__ sums,
                                                   float* __restrict__ cnts) {
  __shared__ int sb[128];
  int n0 = blockIdx.x * 128;
  int j = threadIdx.x;
  int count = min(128, NN - n0);
  if (count <= 0) return;
  for (int t = threadIdx.x; t < count; t += 256) sb[t] = batch[n0 + t];
  __syncthreads();
  float acc = 0.f;
  int run = 0;
  int cur = sb[0];
  for (int i = 0; i < count; ++i) {
    int b = sb[i];
    if (b != cur) {
      atomicAdd(&sums[(size_t)cur * 256 + j], acc);
      if (j == 0) atomicAdd(&cnts[cur], (float)run);
      acc = 0.f;
      run = 0;
      cur = b;
    }
    acc += bf2f(h[(size_t)(n0 + i) * 256 + j]);
    run++;
  }
  atomicAdd(&sums[(size_t)cur * 256 + j], acc);
  if (j == 0) atomicAdd(&cnts[cur], (float)run);
}

// ---------- post-MLP head: one block per graph ----------
__global__ __launch_bounds__(128) void head_kernel(const float* __restrict__ sums,
                                                   const float* __restrict__ cnts,
                                                   const float* __restrict__ p1_w,
                                                   const float* __restrict__ p1_b,
                                                   const float* __restrict__ ln_g,
                                                   const float* __restrict__ ln_b,
                                                   const float* __restrict__ p2_w,
                                                   const float* __restrict__ p2_b,
                                                   const float* __restrict__ hc_w,
                                                   const float* __restrict__ hc_b,
                                                   const float* __restrict__ hf_w,
                                                   const float* __restrict__ hf_b,
                                                   float* __restrict__ out) {
  int g = blockIdx.x;
  int j = threadIdx.x;  // 0..127
  __shared__ float sp[256], st[128], sz[64];
  float cnt = fmaxf(cnts[g], 1.0f);
  for (int t = j; t < 256; t += 128) sp[t] = sums[(size_t)g * 256 + t] / cnt;
  __syncthreads();
  float acc = p1_b[j];
  for (int k = 0; k < 256; k++) acc += sp[k] * p1_w[(size_t)k * 128 + j];
  st[j] = acc;
  __syncthreads();
  float mu = 0.f;
  for (int k = 0; k < 128; k++) mu += st[k];
  mu *= (1.f / 128.f);
  float var = 0.f;
  for (int k = 0; k < 128; k++) {
    float d = st[k] - mu;
    var += d * d;
  }
  var *= (1.f / 128.f);
  float tj = (acc - mu) * rsqrtf(var + 1e-5f) * ln_g[j] + ln_b[j];
  tj = fmaxf(tj, 0.f);
  __syncthreads();
  st[j] = tj;
  __syncthreads();
  if (j < 64) {
    float z = p2_b[j];
    for (int k = 0; k < 128; k++) z += st[k] * p2_w[(size_t)k * 64 + j];
    z = fmaxf(z, 0.f);
    sz[j] = z;
    out[500 + (size_t)g * 64 + j] = z;  // output 2: z [B,64]
  }
  __syncthreads();
  if (j == 0) {
    float c = hc_b[0];
    for (int k = 0; k < 64; k++) c += sz[k] * hc_w[k];
    out[g] = c;  // output 0: cooling [B]
  }
  if (j >= 1 && j < 10) {
    int f = j - 1;
    float v = hf_b[f];
    for (int k = 0; k < 64; k++) v += sz[k] * hf_w[(size_t)k * 9 + f];
    out[50 + (size_t)g * 9 + f] = v;  // output 1: fatigue [B,9]
  }
}

extern "C" void kernel_launch(void* const* d_in, const int* in_sizes, int n_in,
                              void* d_out, int out_size, void* d_ws, size_t ws_size,
                              hipStream_t stream) {
  const float* x = (const float*)d_in[0];
  const int* ei = (const int*)d_in[1];
  const float* ea = (const float*)d_in[2];
  const int* batch = (const int*)d_in[3];
  const float* enc_w = (const float*)d_in[4];
  const float* enc_b = (const float*)d_in[5];
  const float* g1_wl = (const float*)d_in[6];
  const float* g1_bl = (const float*)d_in[7];
  const float* g1_wr = (const float*)d_in[8];
  const float* g1_br = (const float*)d_in[9];
  const float* g1_we = (const float*)d_in[10];
  const float* g1_att = (const float*)d_in[11];
  const float* g1_bias = (const float*)d_in[12];
  const float* g2_wl = (const float*)d_in[13];
  const float* g2_bl = (const float*)d_in[14];
  const float* g2_wr = (const float*)d_in[15];
  const float* g2_br = (const float*)d_in[16];
  const float* g2_we = (const float*)d_in[17];
  const float* g2_att = (const float*)d_in[18];
  const float* g2_bias = (const float*)d_in[19];
  const float* p1_w = (const float*)d_in[20];
  const float* p1_b = (const float*)d_in[21];
  const float* ln_g = (const float*)d_in[22];
  const float* ln_b = (const float*)d_in[23];
  const float* p2_w = (const float*)d_in[24];
  const float* p2_b = (const float*)d_in[25];
  const float* hc_w = (const float*)d_in[26];
  const float* hc_b = (const float*)d_in[27];
  const float* hf_w = (const float*)d_in[28];
  const float* hf_b = (const float*)d_in[29];
  float* out = (float*)d_out;

  // ---- workspace layout ----
  ushort* xlb = (ushort*)d_ws;               // N*256 bf16
  ushort* xrb = xlb + (size_t)NN * 256;      // N*256 bf16
  ushort* hb = xrb + (size_t)NN * 256;       // N*256 bf16
  ushort* h0b = hb + (size_t)NN * 256;       // N*64 bf16
  ushort* w1l = h0b + (size_t)NN * 64;       // 256*64 bf16 (transposed)
  ushort* w1r = w1l + 256 * 64;
  ushort* w2l = w1r + 256 * 64;              // 256*256 bf16
  ushort* w2r = w2l + 256 * 256;
  int2* sedge = (int2*)(w2r + 256 * 256);    // EP+4 (src, ea-bits); padded
  int* counts = (int*)(sedge + EP + 4);      // NN
  int* offsets = counts + NN;                // NN
  int* cursor = offsets + NN;                // NN
  int* bsum = cursor + NN;                   // NBLK_SCAN
  float* sums = (float*)(bsum + NBLK_SCAN);  // B*256
  float* cnts = sums + (size_t)NB * 256;     // B
  float* esum = cnts + NB;                   // 1

  // ---- edge_attr mean + dst histogram (fused) ----
  hipMemsetAsync(esum, 0, sizeof(float), stream);
  hipMemsetAsync(counts, 0, (size_t)NN * sizeof(int), stream);
  prep_kernel<<<1024, 256, 0, stream>>>(ea, esum, ei, counts);

  // ---- counting sort of edges by dst (graph static: reused by both layers) ----
  scanA_kernel<<<NBLK_SCAN, 256, 0, stream>>>(counts, bsum);
  scanB_kernel<<<1, 256, 0, stream>>>(bsum);
  scanC_kernel<<<NBLK_SCAN, 256, 0, stream>>>(counts, bsum, offsets, cursor);
  scatter_kernel<<<1024, 256, 0, stream>>>(ei, ea, esum, cursor, sedge);

  // ---- weight conversion (all four in one) ----
  wconv_all<<<640, 256, 0, stream>>>(g1_wl, g1_wr, g2_wl, g2_wr, w1l, w1r, w2l, w2r);

  // ---- encoder ----
  encoder_kernel<<<(NN * 64 + 255) / 256, 256, 0, stream>>>(x, enc_w, enc_b, h0b);

  const dim3 gemmGrid((NN + GEMM_ROWS - 1) / GEMM_ROWS, 2);
  const int nGatBlocks = (NN + 3) / 4;

  // ================= GAT layer 1 (K=64) =================
  dual_linear_pb<64><<<gemmGrid, 256, 0, stream>>>(h0b, w1l, w1r, g1_bl, g1_br, xlb, xrb);
  gat_fused_kernel<<<nGatBlocks, 256, 0, stream>>>(offsets, counts, sedge, xlb, xrb,
                                                   g1_we, g1_att, g1_bias, hb);

  // ================= GAT layer 2 (K=256) =================
  dual_linear_pb<256><<<gemmGrid, 256, 0, stream>>>(hb, w2l, w2r, g2_bl, g2_br, xlb, xrb);
  gat_fused_kernel<<<nGatBlocks, 256, 0, stream>>>(offsets, counts, sedge, xlb, xrb,
                                                   g2_we, g2_att, g2_bias, hb);

  // ================= pool + head =================
  hipMemsetAsync(sums, 0, (size_t)NB * 256 * sizeof(float), stream);
  hipMemsetAsync(cnts, 0, (size_t)NB * sizeof(float), stream);
  pool_kernel<<<(NN + 127) / 128, 256, 0, stream>>>(hb, batch, sums, cnts);
  head_kernel<<<NB, 128, 0, stream>>>(sums, cnts, p1_w, p1_b, ln_g, ln_b, p2_w, p2_b,
                                      hc_w, hc_b, hf_w, hf_b, out);
}